// Round 2
// baseline (178212.585 us; speedup 1.0000x reference)
//
#include <hip/hip_runtime.h>

#define TT 168
#define HH 64
#define GG 256   // 4*HH gates
#define DD 7
#define NS 8     // samples per block
#define BB 8192

typedef float f32x16 __attribute__((ext_vector_type(16)));
typedef float f32x8  __attribute__((ext_vector_type(8)));

__device__ __forceinline__ float sig_(float v) {
    return 1.0f / (1.0f + __expf(-v));
}
__device__ __forceinline__ float th_(float v) {
    return 1.0f - 2.0f / (__expf(2.0f * v) + 1.0f);
}
__device__ __forceinline__ f32x8 splat8(float v) {
    return (f32x8){v, v, v, v, v, v, v, v};
}

// acc += h_row(j) * w[j] for 16 consecutive j, weights from an SSA f32x16.
#define DOT16(HB, B0, W)                                      \
    _Pragma("unroll")                                         \
    for (int jj = 0; jj < 16; ++jj) {                         \
        const f32x8 hr = *(const f32x8*)(&HB[(B0) + jj][0]);  \
        acc += hr * (W)[jj];                                  \
    }

__global__ __launch_bounds__(256, 2)
void weather_lstm_fused(const float* __restrict__ x,
                        const float* __restrict__ w_ih0, const float* __restrict__ w_hh0,
                        const float* __restrict__ b_ih0, const float* __restrict__ b_hh0,
                        const float* __restrict__ w_ih1, const float* __restrict__ w_hh1,
                        const float* __restrict__ b_ih1, const float* __restrict__ b_hh1,
                        const float* __restrict__ fc_w, const float* __restrict__ fc_b,
                        float* __restrict__ out)
{
    __shared__ __align__(32) float xT[TT][DD][NS];   // 37.6 KB, x transposed per block
    __shared__ __align__(32) float h1buf[HH][NS];    // 2 KB
    __shared__ __align__(32) float h2buf[HH][NS];    // 2 KB
    __shared__ __align__(32) float gbuf[NS][GG + 8]; // 8.25 KB, +8 pad -> 2-way-free reads

    const int g  = threadIdx.x;       // gate index 0..255
    const int s0 = blockIdx.x * NS;   // first sample of this block

    // ---- weights as SSA vector values (cannot be demoted to scratch alloca) ----
    const f32x16 wh0a = *(const f32x16*)(w_hh0 + (size_t)g * HH);
    const f32x16 wh0b = *(const f32x16*)(w_hh0 + (size_t)g * HH + 16);
    const f32x16 wh0c = *(const f32x16*)(w_hh0 + (size_t)g * HH + 32);
    const f32x16 wh0d = *(const f32x16*)(w_hh0 + (size_t)g * HH + 48);
    const f32x16 wi1a = *(const f32x16*)(w_ih1 + (size_t)g * HH);
    const f32x16 wi1b = *(const f32x16*)(w_ih1 + (size_t)g * HH + 16);
    const f32x16 wi1c = *(const f32x16*)(w_ih1 + (size_t)g * HH + 32);
    const f32x16 wi1d = *(const f32x16*)(w_ih1 + (size_t)g * HH + 48);
    const f32x16 wh1a = *(const f32x16*)(w_hh1 + (size_t)g * HH);
    const f32x16 wh1b = *(const f32x16*)(w_hh1 + (size_t)g * HH + 16);
    const f32x16 wh1c = *(const f32x16*)(w_hh1 + (size_t)g * HH + 32);
    const f32x16 wh1d = *(const f32x16*)(w_hh1 + (size_t)g * HH + 48);
    f32x8 wx;
#pragma unroll
    for (int d = 0; d < 8; ++d) wx[d] = (d < DD) ? w_ih0[g * DD + d] : 0.0f;
    const float bias0 = b_ih0[g] + b_hh0[g];
    const float bias1 = b_ih1[g] + b_hh1[g];

    // ---- stage the whole x tile for this block's 8 samples, transposed ----
    for (int i = g; i < NS * TT * DD; i += GG) {
        const int s = i / (TT * DD);
        const int r = i - s * (TT * DD);
        const int t = r / DD;
        const int d = r - t * DD;
        xT[t][d][s] = x[(size_t)(s0 + s) * (TT * DD) + r];
    }

    // zero hidden state
    ((float*)h1buf)[g]      = 0.0f;
    ((float*)h1buf)[g + GG] = 0.0f;
    ((float*)h2buf)[g]      = 0.0f;
    ((float*)h2buf)[g + GG] = 0.0f;

    const int gt = g >> 6;           // gate type 0=i 1=f 2=g 3=o (wave-uniform)
    const int ju = g >> 2;           // hidden unit this thread updates
    const int su = (g & 3) * 2;      // first of 2 sample slots
    float c1a = 0.0f, c1b = 0.0f, c2a = 0.0f, c2b = 0.0f;

    __syncthreads();

    for (int t = 0; t < TT; ++t) {
        // ================= Phase A: layer-0 gates =================
        f32x8 acc = splat8(bias0);
#pragma unroll
        for (int d = 0; d < DD; ++d) {
            const f32x8 xr = *(const f32x8*)(&xT[t][d][0]);
            acc += xr * wx[d];
        }
        DOT16(h1buf, 0,  wh0a)
        DOT16(h1buf, 16, wh0b)
        DOT16(h1buf, 32, wh0c)
        DOT16(h1buf, 48, wh0d)
        // activation applied by the gate-owning thread (wave-uniform branch)
#pragma unroll
        for (int s = 0; s < NS; ++s)
            gbuf[s][g] = (gt == 2) ? th_(acc[s]) : sig_(acc[s]);
        __syncthreads();

        // ---- layer-0 state update (2 slots per thread) ----
        {
            const float i0 = gbuf[su][ju],          i1 = gbuf[su + 1][ju];
            const float f0 = gbuf[su][HH + ju],     f1 = gbuf[su + 1][HH + ju];
            const float g0 = gbuf[su][2 * HH + ju], g1 = gbuf[su + 1][2 * HH + ju];
            const float o0 = gbuf[su][3 * HH + ju], o1 = gbuf[su + 1][3 * HH + ju];
            c1a = f0 * c1a + i0 * g0;
            c1b = f1 * c1b + i1 * g1;
            h1buf[ju][su]     = o0 * th_(c1a);
            h1buf[ju][su + 1] = o1 * th_(c1b);
        }
        __syncthreads();

        // ================= Phase B: layer-1 gates =================
        acc = splat8(bias1);
        DOT16(h1buf, 0,  wi1a)
        DOT16(h1buf, 16, wi1b)
        DOT16(h1buf, 32, wi1c)
        DOT16(h1buf, 48, wi1d)
        DOT16(h2buf, 0,  wh1a)
        DOT16(h2buf, 16, wh1b)
        DOT16(h2buf, 32, wh1c)
        DOT16(h2buf, 48, wh1d)
#pragma unroll
        for (int s = 0; s < NS; ++s)
            gbuf[s][g] = (gt == 2) ? th_(acc[s]) : sig_(acc[s]);
        __syncthreads();

        // ---- layer-1 state update ----
        {
            const float i0 = gbuf[su][ju],          i1 = gbuf[su + 1][ju];
            const float f0 = gbuf[su][HH + ju],     f1 = gbuf[su + 1][HH + ju];
            const float g0 = gbuf[su][2 * HH + ju], g1 = gbuf[su + 1][2 * HH + ju];
            const float o0 = gbuf[su][3 * HH + ju], o1 = gbuf[su + 1][3 * HH + ju];
            c2a = f0 * c2a + i0 * g0;
            c2b = f1 * c2b + i1 * g1;
            h2buf[ju][su]     = o0 * th_(c2a);
            h2buf[ju][su + 1] = o1 * th_(c2b);
        }
        __syncthreads();
    }

    // ================= FC head on final h2 =================
    if (g < NS * 4) {
        const int s = g >> 2, k = g & 3;
        float a = fc_b[k];
#pragma unroll
        for (int j = 0; j < HH; ++j)
            a = fmaf(h2buf[j][s], fc_w[k * HH + j], a);
        out[(size_t)(s0 + s) * 4 + k] = a;
    }
}

extern "C" void kernel_launch(void* const* d_in, const int* in_sizes, int n_in,
                              void* d_out, int out_size, void* d_ws, size_t ws_size,
                              hipStream_t stream) {
    const float* x     = (const float*)d_in[0];
    const float* w_ih0 = (const float*)d_in[1];
    const float* w_hh0 = (const float*)d_in[2];
    const float* b_ih0 = (const float*)d_in[3];
    const float* b_hh0 = (const float*)d_in[4];
    const float* w_ih1 = (const float*)d_in[5];
    const float* w_hh1 = (const float*)d_in[6];
    const float* b_ih1 = (const float*)d_in[7];
    const float* b_hh1 = (const float*)d_in[8];
    const float* fc_w  = (const float*)d_in[9];
    const float* fc_b  = (const float*)d_in[10];
    float* out = (float*)d_out;

    dim3 grid(BB / NS), block(256);
    weather_lstm_fused<<<grid, block, 0, stream>>>(
        x, w_ih0, w_hh0, b_ih0, b_hh0,
        w_ih1, w_hh1, b_ih1, b_hh1, fc_w, fc_b, out);
}

// Round 3
// 84343.298 us; speedup vs baseline: 2.1129x; 2.1129x over previous
//
#include <hip/hip_runtime.h>

#define TT 168
#define HH 64
#define GG 256   // 4*HH gates
#define DD 7
#define NS 8     // samples per block
#define BB 8192
#define NTH 512  // threads per block: (gate g = tid>>1, half hf = tid&1)

typedef float f32x2 __attribute__((ext_vector_type(2)));
typedef float f32x4 __attribute__((ext_vector_type(4)));
typedef float f32x8 __attribute__((ext_vector_type(8)));

__device__ __forceinline__ float sig_(float v) { return 1.0f / (1.0f + __expf(-v)); }
__device__ __forceinline__ float th_(float v)  { return 1.0f - 2.0f / (__expf(2.0f * v) + 1.0f); }

__global__ __launch_bounds__(NTH, 2)
void weather_lstm_fused(const float* __restrict__ x,
                        const float* __restrict__ w_ih0, const float* __restrict__ w_hh0,
                        const float* __restrict__ b_ih0, const float* __restrict__ b_hh0,
                        const float* __restrict__ w_ih1, const float* __restrict__ w_hh1,
                        const float* __restrict__ b_ih1, const float* __restrict__ b_hh1,
                        const float* __restrict__ fc_w, const float* __restrict__ fc_b,
                        float* __restrict__ out)
{
    __shared__ __align__(16) float xT[TT][8][NS];    // 42 KB (d padded to 8, pad zeroed)
    __shared__ __align__(16) float h1buf[HH][NS];    // 2 KB
    __shared__ __align__(16) float h2buf[HH][NS];    // 2 KB
    __shared__ __align__(16) float gbufT[NS][GG];    // 8 KB  (gbufT[s][gate])

    const int tid = threadIdx.x;
    const int g   = tid >> 1;       // gate 0..255
    const int hf  = tid & 1;        // which half of the j-range this thread sums
    const int s0  = blockIdx.x * NS;

    // ---- per-thread HALF weight rows: ~100 floats -> fits under 128 VGPR ----
    const size_t ro = (size_t)g * HH + hf * 32;
    f32x4 wh0[8], wi1[8], wh1[8];
#pragma unroll
    for (int k = 0; k < 8; ++k) wh0[k] = *(const f32x4*)(w_hh0 + ro + 4 * k);
#pragma unroll
    for (int k = 0; k < 8; ++k) wi1[k] = *(const f32x4*)(w_ih1 + ro + 4 * k);
#pragma unroll
    for (int k = 0; k < 8; ++k) wh1[k] = *(const f32x4*)(w_hh1 + ro + 4 * k);
    float wx[4];
#pragma unroll
    for (int k = 0; k < 4; ++k) {
        const int d = hf * 4 + k;
        wx[k] = (d < DD) ? w_ih0[g * DD + d] : 0.0f;
    }
    // bias added by half 0 only (halves are summed via shuffle)
    const float bias0 = hf ? 0.0f : (b_ih0[g] + b_hh0[g]);
    const float bias1 = hf ? 0.0f : (b_ih1[g] + b_hh1[g]);
    const int   gt    = g >> 6;     // gate type (wave-uniform: g spans 32 per wave)
    const int   hj    = hf * 32;    // j-range base for the h dot products
    const int   hd    = hf * 4;     // d-range base for the x dot product

    // ---- stage x tile transposed: xT[t][d][s], d==7 plane zeroed ----
    for (int i = tid; i < NS * TT * 8; i += NTH) {
        const int s = i / (TT * 8);
        const int r = i - s * (TT * 8);
        const int t = r >> 3;
        const int d = r & 7;
        float v = 0.0f;
        if (d < DD) v = x[(size_t)(s0 + s) * (TT * DD) + t * DD + d];
        xT[t][d][s] = v;
    }
    // zero hidden state
    ((float*)h1buf)[tid] = 0.0f;
    ((float*)h2buf)[tid] = 0.0f;

    // state-update role (threads 0..255 only; waves 0-3 -> clean wave split)
    const int ju = tid >> 2;
    const int su = (tid & 3) * 2;
    float c1a = 0.0f, c1b = 0.0f, c2a = 0.0f, c2b = 0.0f;

    __syncthreads();

    for (int t = 0; t < TT; ++t) {
        // ================= Phase A: layer-0 gate halves =================
        f32x8 acc = {bias0, bias0, bias0, bias0, bias0, bias0, bias0, bias0};
#pragma unroll
        for (int k = 0; k < 4; ++k) {
            const f32x8 xr = *(const f32x8*)(&xT[t][hd + k][0]);
            acc += xr * wx[k];
        }
#pragma unroll
        for (int j = 0; j < 32; ++j) {
            const f32x8 hr = *(const f32x8*)(&h1buf[hj + j][0]);
            acc += hr * wh0[j >> 2][j & 3];
        }
        // combine halves (adjacent lanes), both lanes get the full sum
#pragma unroll
        for (int k = 0; k < 8; ++k) acc[k] += __shfl_xor(acc[k], 1, 64);
        // activation: even lane writes s=0..3, odd lane s=4..7 (2-way free)
#pragma unroll
        for (int k = 0; k < 4; ++k) {
            const float v = hf ? acc[4 + k] : acc[k];   // constant extracts only
            gbufT[hd + k][g] = (gt == 2) ? th_(v) : sig_(v);
        }
        __syncthreads();

        // ---- layer-0 state update (threads 0..255, 2 slots each) ----
        if (tid < 256) {
            const float i0 = gbufT[su][ju],           i1 = gbufT[su + 1][ju];
            const float f0 = gbufT[su][HH + ju],      f1 = gbufT[su + 1][HH + ju];
            const float g0 = gbufT[su][2 * HH + ju],  g1 = gbufT[su + 1][2 * HH + ju];
            const float o0 = gbufT[su][3 * HH + ju],  o1 = gbufT[su + 1][3 * HH + ju];
            c1a = f0 * c1a + i0 * g0;
            c1b = f1 * c1b + i1 * g1;
            *(f32x2*)(&h1buf[ju][su]) = (f32x2){o0 * th_(c1a), o1 * th_(c1b)};
        }
        __syncthreads();

        // ================= Phase B: layer-1 gate halves =================
        acc = (f32x8){bias1, bias1, bias1, bias1, bias1, bias1, bias1, bias1};
#pragma unroll
        for (int j = 0; j < 32; ++j) {
            const f32x8 hr = *(const f32x8*)(&h1buf[hj + j][0]);
            acc += hr * wi1[j >> 2][j & 3];
        }
#pragma unroll
        for (int j = 0; j < 32; ++j) {
            const f32x8 hr = *(const f32x8*)(&h2buf[hj + j][0]);
            acc += hr * wh1[j >> 2][j & 3];
        }
#pragma unroll
        for (int k = 0; k < 8; ++k) acc[k] += __shfl_xor(acc[k], 1, 64);
#pragma unroll
        for (int k = 0; k < 4; ++k) {
            const float v = hf ? acc[4 + k] : acc[k];
            gbufT[hd + k][g] = (gt == 2) ? th_(v) : sig_(v);
        }
        __syncthreads();

        // ---- layer-1 state update ----
        if (tid < 256) {
            const float i0 = gbufT[su][ju],           i1 = gbufT[su + 1][ju];
            const float f0 = gbufT[su][HH + ju],      f1 = gbufT[su + 1][HH + ju];
            const float g0 = gbufT[su][2 * HH + ju],  g1 = gbufT[su + 1][2 * HH + ju];
            const float o0 = gbufT[su][3 * HH + ju],  o1 = gbufT[su + 1][3 * HH + ju];
            c2a = f0 * c2a + i0 * g0;
            c2b = f1 * c2b + i1 * g1;
            *(f32x2*)(&h2buf[ju][su]) = (f32x2){o0 * th_(c2a), o1 * th_(c2b)};
        }
        __syncthreads();
    }

    // ================= FC head on final h2 =================
    if (tid < NS * 4) {
        const int s = tid >> 2, k = tid & 3;
        float a = fc_b[k];
#pragma unroll
        for (int j = 0; j < HH; ++j)
            a = fmaf(h2buf[j][s], fc_w[k * HH + j], a);
        out[(size_t)(s0 + s) * 4 + k] = a;
    }
}

extern "C" void kernel_launch(void* const* d_in, const int* in_sizes, int n_in,
                              void* d_out, int out_size, void* d_ws, size_t ws_size,
                              hipStream_t stream) {
    const float* x     = (const float*)d_in[0];
    const float* w_ih0 = (const float*)d_in[1];
    const float* w_hh0 = (const float*)d_in[2];
    const float* b_ih0 = (const float*)d_in[3];
    const float* b_hh0 = (const float*)d_in[4];
    const float* w_ih1 = (const float*)d_in[5];
    const float* w_hh1 = (const float*)d_in[6];
    const float* b_ih1 = (const float*)d_in[7];
    const float* b_hh1 = (const float*)d_in[8];
    const float* fc_w  = (const float*)d_in[9];
    const float* fc_b  = (const float*)d_in[10];
    float* out = (float*)d_out;

    dim3 grid(BB / NS), block(NTH);
    weather_lstm_fused<<<grid, block, 0, stream>>>(
        x, w_ih0, w_hh0, b_ih0, b_hh0,
        w_ih1, w_hh1, b_ih1, b_hh1, fc_w, fc_b, out);
}

// Round 4
// 849.182 us; speedup vs baseline: 209.8637x; 99.3229x over previous
//
#include <hip/hip_runtime.h>

#define TT 168
#define HH 64
#define DD 7
#define NS 16      // samples per block (M of the MFMA tiles)
#define BB 8192

typedef float f32x4 __attribute__((ext_vector_type(4)));
typedef short bf16x8 __attribute__((ext_vector_type(8)));

#define MFMA16(A, B, C) __builtin_amdgcn_mfma_f32_16x16x32_bf16((A), (B), (C), 0, 0, 0)

// 3-term split-precision product accumulate: (Ah+Al)*(Bh+Bl) ~= Ah*Bh + Al*Bh + Ah*Bl
#define TERM3(G, Ah, Al, Bh, Bl)  \
    G = MFMA16(Ah, Bh, G);        \
    G = MFMA16(Al, Bh, G);        \
    G = MFMA16(Ah, Bl, G);

__device__ __forceinline__ unsigned short bf16r(float v) {   // round-to-nearest bf16
    union { float f; unsigned u; } x; x.f = v;
    unsigned r = x.u + 0x7FFFu + ((x.u >> 16) & 1u);
    return (unsigned short)(r >> 16);
}
__device__ __forceinline__ float bf2f(unsigned short h) {
    union { unsigned u; float f; } x; x.u = ((unsigned)h) << 16; return x.f;
}
__device__ __forceinline__ void split8(f32x4 a, f32x4 b, bf16x8& hi, bf16x8& lo) {
#pragma unroll
    for (int e = 0; e < 4; ++e) {
        unsigned short h = bf16r(a[e]);
        hi[e] = (short)h;
        lo[e] = (short)bf16r(a[e] - bf2f(h));
    }
#pragma unroll
    for (int e = 0; e < 4; ++e) {
        unsigned short h = bf16r(b[e]);
        hi[4 + e] = (short)h;
        lo[4 + e] = (short)bf16r(b[e] - bf2f(h));
    }
}
__device__ __forceinline__ void unpack8(uint4 w0, uint4 w1, bf16x8& hi, bf16x8& lo) {
    hi[0] = (short)(w0.x); lo[0] = (short)(w0.x >> 16);
    hi[1] = (short)(w0.y); lo[1] = (short)(w0.y >> 16);
    hi[2] = (short)(w0.z); lo[2] = (short)(w0.z >> 16);
    hi[3] = (short)(w0.w); lo[3] = (short)(w0.w >> 16);
    hi[4] = (short)(w1.x); lo[4] = (short)(w1.x >> 16);
    hi[5] = (short)(w1.y); lo[5] = (short)(w1.y >> 16);
    hi[6] = (short)(w1.z); lo[6] = (short)(w1.z >> 16);
    hi[7] = (short)(w1.w); lo[7] = (short)(w1.w >> 16);
}
__device__ __forceinline__ float sigf(float v) { return 1.0f / (1.0f + __expf(-v)); }
__device__ __forceinline__ float thf(float v)  { return 1.0f - 2.0f / (__expf(2.0f * v) + 1.0f); }

__global__ __launch_bounds__(256, 1)
void weather_lstm_mfma(const float* __restrict__ x,
                       const float* __restrict__ w_ih0, const float* __restrict__ w_hh0,
                       const float* __restrict__ b_ih0, const float* __restrict__ b_hh0,
                       const float* __restrict__ w_ih1, const float* __restrict__ w_hh1,
                       const float* __restrict__ b_ih1, const float* __restrict__ b_hh1,
                       const float* __restrict__ fc_w, const float* __restrict__ fc_b,
                       float* __restrict__ out)
{
    // x pre-split into frag-ready hi/lo bf16x8 (k=0..6 data, k=7 zero)
    __shared__ bf16x8 xs_hi[TT][NS];          // 43008 B
    __shared__ bf16x8 xs_lo[TT][NS];          // 43008 B
    // h exchange: packed (lo16<<16)|hi16 per value, [sample][unit], row = 272B (16B-mult)
    __shared__ unsigned hb1[NS][68];          // 4352 B
    __shared__ unsigned hb2[NS][68];          // 4352 B

    const int tid  = threadIdx.x;
    const int q    = tid >> 6;       // wave id = unit-group (units 16q..16q+15)
    const int lane = tid & 63;
    const int col  = lane & 15;      // B col / C col / A row index
    const int kg   = lane >> 4;      // k-group (k = 32*kf + 8*kg + e)
    const int s0   = blockIdx.x * NS;

    // ---------------- stage x (once), split + pack ----------------
    for (int i = tid; i < NS * TT; i += 256) {
        const int s = i / TT, t = i - s * TT;
        const float* px = x + ((size_t)(s0 + s) * TT + t) * DD;
        f32x4 a, b;
        a[0] = px[0]; a[1] = px[1]; a[2] = px[2]; a[3] = px[3];
        b[0] = px[4]; b[1] = px[5]; b[2] = px[6]; b[3] = 0.0f;
        bf16x8 hi, lo;
        split8(a, b, hi, lo);
        xs_hi[t][s] = hi; xs_lo[t][s] = lo;
    }

    // ---------------- stationary weight fragments ----------------
    // wave q, tile t4 (=gate type i,f,g,o) covers gate rows: 64*t4 + 16*q + col
    bf16x8 B0h[4][2], B0l[4][2];   // w_hh0   (K=64,  kf 0..1)
    bf16x8 BXh[4],    BXl[4];      // w_ih0   (K=7 in kf 0)
    bf16x8 B1h[4][4], B1l[4][4];   // [w_ih1 | w_hh1] (K=128, kf 0..3)
    float bias0[4], bias1[4];
#pragma unroll
    for (int t4 = 0; t4 < 4; ++t4) {
        const int row = 64 * t4 + 16 * q + col;
        bias0[t4] = b_ih0[row] + b_hh0[row];
        bias1[t4] = b_ih1[row] + b_hh1[row];
#pragma unroll
        for (int kf = 0; kf < 2; ++kf) {
            const float* p = w_hh0 + (size_t)row * HH + 32 * kf + 8 * kg;
            f32x4 a = *(const f32x4*)p, b = *(const f32x4*)(p + 4);
            split8(a, b, B0h[t4][kf], B0l[t4][kf]);
        }
#pragma unroll
        for (int kf = 0; kf < 4; ++kf) {
            const float* base = (kf < 2) ? (w_ih1 + (size_t)row * HH + 32 * kf)
                                         : (w_hh1 + (size_t)row * HH + 32 * (kf - 2));
            const float* p = base + 8 * kg;
            f32x4 a = *(const f32x4*)p, b = *(const f32x4*)(p + 4);
            split8(a, b, B1h[t4][kf], B1l[t4][kf]);
        }
        {
            f32x4 a = {0, 0, 0, 0}, b = {0, 0, 0, 0};
            if (kg == 0) {
                const float* p = w_ih0 + (size_t)row * DD;
                a[0] = p[0]; a[1] = p[1]; a[2] = p[2]; a[3] = p[3];
                b[0] = p[4]; b[1] = p[5]; b[2] = p[6];
            }
            split8(a, b, BXh[t4], BXl[t4]);
        }
    }

    // ---------------- recurrent state ----------------
    const bf16x8 z8 = {0, 0, 0, 0, 0, 0, 0, 0};
    bf16x8 A1h[2], A1l[2], A2h[2], A2l[2];
    A1h[0] = z8; A1h[1] = z8; A1l[0] = z8; A1l[1] = z8;
    A2h[0] = z8; A2h[1] = z8; A2l[0] = z8; A2l[1] = z8;
    f32x4 c1 = {0, 0, 0, 0}, c2 = {0, 0, 0, 0};

    __syncthreads();

#pragma unroll 1
    for (int t = 0; t < TT; ++t) {
        // x fragment (rows = samples = col; only k-group 0 holds data)
        bf16x8 axh = z8, axl = z8;
        if (kg == 0) { axh = xs_hi[t][col]; axl = xs_lo[t][col]; }

        // ----- layer 0 gates: C = bias + x*Wx + h1*W0 -----
        f32x4 g0 = {bias0[0], bias0[0], bias0[0], bias0[0]};
        f32x4 g1 = {bias0[1], bias0[1], bias0[1], bias0[1]};
        f32x4 g2 = {bias0[2], bias0[2], bias0[2], bias0[2]};
        f32x4 g3 = {bias0[3], bias0[3], bias0[3], bias0[3]};
        TERM3(g0, axh, axl, BXh[0], BXl[0])
        TERM3(g1, axh, axl, BXh[1], BXl[1])
        TERM3(g2, axh, axl, BXh[2], BXl[2])
        TERM3(g3, axh, axl, BXh[3], BXl[3])
        TERM3(g0, A1h[0], A1l[0], B0h[0][0], B0l[0][0])
        TERM3(g1, A1h[0], A1l[0], B0h[1][0], B0l[1][0])
        TERM3(g2, A1h[0], A1l[0], B0h[2][0], B0l[2][0])
        TERM3(g3, A1h[0], A1l[0], B0h[3][0], B0l[3][0])
        TERM3(g0, A1h[1], A1l[1], B0h[0][1], B0l[0][1])
        TERM3(g1, A1h[1], A1l[1], B0h[1][1], B0l[1][1])
        TERM3(g2, A1h[1], A1l[1], B0h[2][1], B0l[2][1])
        TERM3(g3, A1h[1], A1l[1], B0h[3][1], B0l[3][1])

        // ----- layer 0 state update (lane-local: unit=16q+col, samples=4kg+r) -----
        f32x4 h1v;
#pragma unroll
        for (int r = 0; r < 4; ++r) {
            const float iv = sigf(g0[r]), fv = sigf(g1[r]);
            const float gv = thf(g2[r]),  ov = sigf(g3[r]);
            c1[r] = fv * c1[r] + iv * gv;
            h1v[r] = ov * thf(c1[r]);
        }
        {
            const int u = 16 * q + col;
#pragma unroll
            for (int r = 0; r < 4; ++r) {
                unsigned short hi = bf16r(h1v[r]);
                unsigned short lo = bf16r(h1v[r] - bf2f(hi));
                hb1[4 * kg + r][u] = ((unsigned)lo << 16) | (unsigned)hi;
            }
        }
        __syncthreads();
        // rebuild h1 A-fragments (row=sample=col, k=unit)
#pragma unroll
        for (int kf = 0; kf < 2; ++kf) {
            const unsigned* pk = &hb1[col][32 * kf + 8 * kg];
            uint4 w0 = *(const uint4*)pk;
            uint4 w1 = *(const uint4*)(pk + 4);
            unpack8(w0, w1, A1h[kf], A1l[kf]);
        }

        // ----- layer 1 gates: C = bias + [h1|h2]*W1 -----
        g0 = (f32x4){bias1[0], bias1[0], bias1[0], bias1[0]};
        g1 = (f32x4){bias1[1], bias1[1], bias1[1], bias1[1]};
        g2 = (f32x4){bias1[2], bias1[2], bias1[2], bias1[2]};
        g3 = (f32x4){bias1[3], bias1[3], bias1[3], bias1[3]};
        TERM3(g0, A1h[0], A1l[0], B1h[0][0], B1l[0][0])
        TERM3(g1, A1h[0], A1l[0], B1h[1][0], B1l[1][0])
        TERM3(g2, A1h[0], A1l[0], B1h[2][0], B1l[2][0])
        TERM3(g3, A1h[0], A1l[0], B1h[3][0], B1l[3][0])
        TERM3(g0, A1h[1], A1l[1], B1h[0][1], B1l[0][1])
        TERM3(g1, A1h[1], A1l[1], B1h[1][1], B1l[1][1])
        TERM3(g2, A1h[1], A1l[1], B1h[2][1], B1l[2][1])
        TERM3(g3, A1h[1], A1l[1], B1h[3][1], B1l[3][1])
        TERM3(g0, A2h[0], A2l[0], B1h[0][2], B1l[0][2])
        TERM3(g1, A2h[0], A2l[0], B1h[1][2], B1l[1][2])
        TERM3(g2, A2h[0], A2l[0], B1h[2][2], B1l[2][2])
        TERM3(g3, A2h[0], A2l[0], B1h[3][2], B1l[3][2])
        TERM3(g0, A2h[1], A2l[1], B1h[0][3], B1l[0][3])
        TERM3(g1, A2h[1], A2l[1], B1h[1][3], B1l[1][3])
        TERM3(g2, A2h[1], A2l[1], B1h[2][3], B1l[2][3])
        TERM3(g3, A2h[1], A2l[1], B1h[3][3], B1l[3][3])

        // ----- layer 1 state update -----
        f32x4 h2v;
#pragma unroll
        for (int r = 0; r < 4; ++r) {
            const float iv = sigf(g0[r]), fv = sigf(g1[r]);
            const float gv = thf(g2[r]),  ov = sigf(g3[r]);
            c2[r] = fv * c2[r] + iv * gv;
            h2v[r] = ov * thf(c2[r]);
        }
        {
            const int u = 16 * q + col;
#pragma unroll
            for (int r = 0; r < 4; ++r) {
                unsigned short hi = bf16r(h2v[r]);
                unsigned short lo = bf16r(h2v[r] - bf2f(hi));
                hb2[4 * kg + r][u] = ((unsigned)lo << 16) | (unsigned)hi;
            }
        }
        __syncthreads();
#pragma unroll
        for (int kf = 0; kf < 2; ++kf) {
            const unsigned* pk = &hb2[col][32 * kf + 8 * kg];
            uint4 w0 = *(const uint4*)pk;
            uint4 w1 = *(const uint4*)(pk + 4);
            unpack8(w0, w1, A2h[kf], A2l[kf]);
        }
    }

    // ---------------- FC head on final h2 ----------------
    if (tid < NS * 4) {
        const int s = tid >> 2, k = tid & 3;
        float a = fc_b[k];
#pragma unroll
        for (int j = 0; j < HH; ++j) {
            const unsigned v = hb2[s][j];
            union { unsigned u; float f; } hi, lo;
            hi.u = v << 16;
            lo.u = v & 0xFFFF0000u;
            a = fmaf(hi.f + lo.f, fc_w[k * HH + j], a);
        }
        out[(size_t)(s0 + s) * 4 + k] = a;
    }
}

extern "C" void kernel_launch(void* const* d_in, const int* in_sizes, int n_in,
                              void* d_out, int out_size, void* d_ws, size_t ws_size,
                              hipStream_t stream) {
    const float* x     = (const float*)d_in[0];
    const float* w_ih0 = (const float*)d_in[1];
    const float* w_hh0 = (const float*)d_in[2];
    const float* b_ih0 = (const float*)d_in[3];
    const float* b_hh0 = (const float*)d_in[4];
    const float* w_ih1 = (const float*)d_in[5];
    const float* w_hh1 = (const float*)d_in[6];
    const float* b_ih1 = (const float*)d_in[7];
    const float* b_hh1 = (const float*)d_in[8];
    const float* fc_w  = (const float*)d_in[9];
    const float* fc_b  = (const float*)d_in[10];
    float* out = (float*)d_out;

    dim3 grid(BB / NS), block(256);
    weather_lstm_mfma<<<grid, block, 0, stream>>>(
        x, w_ih0, w_hh0, b_ih0, b_hh0,
        w_ih1, w_hh1, b_ih1, b_hh1, fc_w, fc_b, out);
}

// Round 5
// 522.911 us; speedup vs baseline: 340.8085x; 1.6240x over previous
//
#include <hip/hip_runtime.h>

#define TT 168
#define HH 64
#define DD 7
#define NS 16      // samples per block (N of the MFMA tiles now)
#define BB 8192
#define CH 16      // timesteps per staged x chunk
#define NCH ((TT + CH - 1) / CH)   // 11

typedef float f32x4 __attribute__((ext_vector_type(4)));
typedef short bf16x8 __attribute__((ext_vector_type(8)));

#define MFMA16(A, B, C) __builtin_amdgcn_mfma_f32_16x16x32_bf16((A), (B), (C), 0, 0, 0)

// (Wh+Wl)*(Dh+Dl) ~= Wh*Dh + Wl*Dh + Wh*Dl   (W = A-operand weights, D = B-operand data)
#define TERM3(G, Wh, Wl, Dh, Dl)  \
    G = MFMA16(Wh, Dh, G);        \
    G = MFMA16(Wl, Dh, G);        \
    G = MFMA16(Wh, Dl, G);

__device__ __forceinline__ unsigned short bf16r(float v) {   // RTNE bf16
    union { float f; unsigned u; } x; x.f = v;
    unsigned r = x.u + 0x7FFFu + ((x.u >> 16) & 1u);
    return (unsigned short)(r >> 16);
}
__device__ __forceinline__ float bf2f(unsigned short h) {
    union { unsigned u; float f; } x; x.u = ((unsigned)h) << 16; return x.f;
}
__device__ __forceinline__ void split8(f32x4 a, f32x4 b, bf16x8& hi, bf16x8& lo) {
#pragma unroll
    for (int e = 0; e < 4; ++e) {
        unsigned short h = bf16r(a[e]);
        hi[e] = (short)h;
        lo[e] = (short)bf16r(a[e] - bf2f(h));
    }
#pragma unroll
    for (int e = 0; e < 4; ++e) {
        unsigned short h = bf16r(b[e]);
        hi[4 + e] = (short)h;
        lo[4 + e] = (short)bf16r(b[e] - bf2f(h));
    }
}

// fast activations: v_exp_f32 + v_rcp_f32, saturation-safe at +/-inf
__device__ __forceinline__ float sigf(float v) {
    return __builtin_amdgcn_rcpf(1.0f + __builtin_amdgcn_exp2f(v * -1.44269504f));
}
__device__ __forceinline__ float thf(float v) {
    return fmaf(-2.0f, __builtin_amdgcn_rcpf(__builtin_amdgcn_exp2f(v * 2.88539008f) + 1.0f), 1.0f);
}

__global__ __launch_bounds__(256, 1)
void weather_lstm_mfma(const float* __restrict__ x,
                       const float* __restrict__ w_ih0, const float* __restrict__ w_hh0,
                       const float* __restrict__ b_ih0, const float* __restrict__ b_hh0,
                       const float* __restrict__ w_ih1, const float* __restrict__ w_hh1,
                       const float* __restrict__ b_ih1, const float* __restrict__ b_hh1,
                       const float* __restrict__ fc_w, const float* __restrict__ fc_b,
                       float* __restrict__ out)
{
    // x chunks, frag-ready: xs[buf][t][sample] = 8 features hi/lo (16 KB total)
    __shared__ bf16x8 xs_hi[2][CH][NS];
    __shared__ bf16x8 xs_lo[2][CH][NS];
    // h state, frag-ready bf16 [sample][unit], row padded to 72 (144 B) -> 2-way reads
    __shared__ __align__(16) short h1_hi[NS][72], h1_lo[NS][72];
    __shared__ __align__(16) short h2_hi[NS][72], h2_lo[NS][72];

    const int tid  = threadIdx.x;
    const int q    = tid >> 6;       // wave = unit group (units 16q..16q+15)
    const int lane = tid & 63;
    const int col  = lane & 15;      // A row (weight row) / B col (sample) / C col (sample)
    const int kg   = lane >> 4;      // k-group
    const int s0   = blockIdx.x * NS;

    // ---------------- stationary weight fragments (A-operand) ----------------
    // lane (col,kg), tile t4: weight row = 64*t4 + 16*q + col, k = 32*kf + 8*kg + e
    bf16x8 B0h[4][2], B0l[4][2];   // w_hh0   (K=64)
    bf16x8 BXh[4],    BXl[4];      // w_ih0   (K=7, kg==0 only)
    bf16x8 B1h[4][4], B1l[4][4];   // [w_ih1 | w_hh1] (K=128)
    f32x4 bias0[4], bias1[4];      // C rows = units 16q+4kg+{0..3}
#pragma unroll
    for (int t4 = 0; t4 < 4; ++t4) {
        const int row = 64 * t4 + 16 * q + col;
        const int rr  = 64 * t4 + 16 * q + 4 * kg;
        bias0[t4] = *(const f32x4*)(b_ih0 + rr) + *(const f32x4*)(b_hh0 + rr);
        bias1[t4] = *(const f32x4*)(b_ih1 + rr) + *(const f32x4*)(b_hh1 + rr);
#pragma unroll
        for (int kf = 0; kf < 2; ++kf) {
            const float* p = w_hh0 + (size_t)row * HH + 32 * kf + 8 * kg;
            split8(*(const f32x4*)p, *(const f32x4*)(p + 4), B0h[t4][kf], B0l[t4][kf]);
        }
#pragma unroll
        for (int kf = 0; kf < 4; ++kf) {
            const float* base = (kf < 2) ? (w_ih1 + (size_t)row * HH + 32 * kf)
                                         : (w_hh1 + (size_t)row * HH + 32 * (kf - 2));
            const float* p = base + 8 * kg;
            split8(*(const f32x4*)p, *(const f32x4*)(p + 4), B1h[t4][kf], B1l[t4][kf]);
        }
        {
            f32x4 a = {0, 0, 0, 0}, b = {0, 0, 0, 0};
            if (kg == 0) {
                const float* p = w_ih0 + (size_t)row * DD;
                a[0] = p[0]; a[1] = p[1]; a[2] = p[2]; a[3] = p[3];
                b[0] = p[4]; b[1] = p[5]; b[2] = p[6];
            }
            split8(a, b, BXh[t4], BXl[t4]);
        }
    }

    // ---------------- init: zero h, stage chunk 0 ----------------
    for (int i = tid; i < NS * 72; i += 256) {
        ((short*)h1_hi)[i] = 0; ((short*)h1_lo)[i] = 0;
        ((short*)h2_hi)[i] = 0; ((short*)h2_lo)[i] = 0;
    }
    {
        const int tloc = tid & 15, ss = tid >> 4;
        f32x4 a = {0, 0, 0, 0}, b = {0, 0, 0, 0};
        const float* px = x + ((size_t)(s0 + ss) * TT + tloc) * DD;
        a[0] = px[0]; a[1] = px[1]; a[2] = px[2]; a[3] = px[3];
        b[0] = px[4]; b[1] = px[5]; b[2] = px[6];
        bf16x8 hi, lo; split8(a, b, hi, lo);
        xs_hi[0][tloc][ss] = hi; xs_lo[0][tloc][ss] = lo;
    }

    const bf16x8 z8 = {0, 0, 0, 0, 0, 0, 0, 0};
    f32x4 c1 = {0, 0, 0, 0}, c2 = {0, 0, 0, 0};
    const int ub = 16 * q + 4 * kg;          // base unit this lane updates

    __syncthreads();

#pragma unroll 1
    for (int c = 0; c < NCH; ++c) {
        const int buf = c & 1;
        // prefetch next chunk into the other buffer (reads of it are >=16 barriers away)
        if (c + 1 < NCH) {
            const int tloc = tid & 15, ss = tid >> 4;
            const int tg = (c + 1) * CH + tloc;
            f32x4 a = {0, 0, 0, 0}, b = {0, 0, 0, 0};
            if (tg < TT) {
                const float* px = x + ((size_t)(s0 + ss) * TT + tg) * DD;
                a[0] = px[0]; a[1] = px[1]; a[2] = px[2]; a[3] = px[3];
                b[0] = px[4]; b[1] = px[5]; b[2] = px[6];
            }
            bf16x8 hi, lo; split8(a, b, hi, lo);
            xs_hi[buf ^ 1][tloc][ss] = hi; xs_lo[buf ^ 1][tloc][ss] = lo;
        }
        const int tmax = (c == NCH - 1) ? (TT - (NCH - 1) * CH) : CH;

#pragma unroll 1
        for (int tt = 0; tt < tmax; ++tt) {
            // ----- layer 0 gates: C[unit][sample] -----
            bf16x8 axh = z8, axl = z8;
            if (kg == 0) { axh = xs_hi[buf][tt][col]; axl = xs_lo[buf][tt][col]; }

            f32x4 g0 = bias0[0], g1 = bias0[1], g2 = bias0[2], g3 = bias0[3];
            TERM3(g0, BXh[0], BXl[0], axh, axl)
            TERM3(g1, BXh[1], BXl[1], axh, axl)
            TERM3(g2, BXh[2], BXl[2], axh, axl)
            TERM3(g3, BXh[3], BXl[3], axh, axl)
            {
                const bf16x8 dh = *(const bf16x8*)&h1_hi[col][8 * kg];
                const bf16x8 dl = *(const bf16x8*)&h1_lo[col][8 * kg];
                TERM3(g0, B0h[0][0], B0l[0][0], dh, dl)
                TERM3(g1, B0h[1][0], B0l[1][0], dh, dl)
                TERM3(g2, B0h[2][0], B0l[2][0], dh, dl)
                TERM3(g3, B0h[3][0], B0l[3][0], dh, dl)
            }
            {
                const bf16x8 dh = *(const bf16x8*)&h1_hi[col][32 + 8 * kg];
                const bf16x8 dl = *(const bf16x8*)&h1_lo[col][32 + 8 * kg];
                TERM3(g0, B0h[0][1], B0l[0][1], dh, dl)
                TERM3(g1, B0h[1][1], B0l[1][1], dh, dl)
                TERM3(g2, B0h[2][1], B0l[2][1], dh, dl)
                TERM3(g3, B0h[3][1], B0l[3][1], dh, dl)
            }

            // ----- layer 0 state update: units ub..ub+3, sample col -----
            {
                f32x4 hv;
#pragma unroll
                for (int r = 0; r < 4; ++r) {
                    const float iv = sigf(g0[r]), fv = sigf(g1[r]);
                    const float gv = thf(g2[r]),  ov = sigf(g3[r]);
                    c1[r] = fv * c1[r] + iv * gv;
                    hv[r] = ov * thf(c1[r]);
                }
                unsigned d0, d1, e0, e1;
                asm("v_cvt_pk_bf16_f32 %0, %1, %2" : "=v"(d0) : "v"(hv[0]), "v"(hv[1]));
                asm("v_cvt_pk_bf16_f32 %0, %1, %2" : "=v"(d1) : "v"(hv[2]), "v"(hv[3]));
                const float p0 = __uint_as_float(d0 << 16);
                const float p1 = __uint_as_float(d0 & 0xFFFF0000u);
                const float p2 = __uint_as_float(d1 << 16);
                const float p3 = __uint_as_float(d1 & 0xFFFF0000u);
                asm("v_cvt_pk_bf16_f32 %0, %1, %2" : "=v"(e0) : "v"(hv[0] - p0), "v"(hv[1] - p1));
                asm("v_cvt_pk_bf16_f32 %0, %1, %2" : "=v"(e1) : "v"(hv[2] - p2), "v"(hv[3] - p3));
                *(uint2*)&h1_hi[col][ub] = make_uint2(d0, d1);
                *(uint2*)&h1_lo[col][ub] = make_uint2(e0, e1);
            }
            __syncthreads();

            // ----- layer 1 gates: K = [h1 | h2] -----
            g0 = bias1[0]; g1 = bias1[1]; g2 = bias1[2]; g3 = bias1[3];
            {
                const bf16x8 dh = *(const bf16x8*)&h1_hi[col][8 * kg];
                const bf16x8 dl = *(const bf16x8*)&h1_lo[col][8 * kg];
                TERM3(g0, B1h[0][0], B1l[0][0], dh, dl)
                TERM3(g1, B1h[1][0], B1l[1][0], dh, dl)
                TERM3(g2, B1h[2][0], B1l[2][0], dh, dl)
                TERM3(g3, B1h[3][0], B1l[3][0], dh, dl)
            }
            {
                const bf16x8 dh = *(const bf16x8*)&h1_hi[col][32 + 8 * kg];
                const bf16x8 dl = *(const bf16x8*)&h1_lo[col][32 + 8 * kg];
                TERM3(g0, B1h[0][1], B1l[0][1], dh, dl)
                TERM3(g1, B1h[1][1], B1l[1][1], dh, dl)
                TERM3(g2, B1h[2][1], B1l[2][1], dh, dl)
                TERM3(g3, B1h[3][1], B1l[3][1], dh, dl)
            }
            {
                const bf16x8 dh = *(const bf16x8*)&h2_hi[col][8 * kg];
                const bf16x8 dl = *(const bf16x8*)&h2_lo[col][8 * kg];
                TERM3(g0, B1h[0][2], B1l[0][2], dh, dl)
                TERM3(g1, B1h[1][2], B1l[1][2], dh, dl)
                TERM3(g2, B1h[2][2], B1l[2][2], dh, dl)
                TERM3(g3, B1h[3][2], B1l[3][2], dh, dl)
            }
            {
                const bf16x8 dh = *(const bf16x8*)&h2_hi[col][32 + 8 * kg];
                const bf16x8 dl = *(const bf16x8*)&h2_lo[col][32 + 8 * kg];
                TERM3(g0, B1h[0][3], B1l[0][3], dh, dl)
                TERM3(g1, B1h[1][3], B1l[1][3], dh, dl)
                TERM3(g2, B1h[2][3], B1l[2][3], dh, dl)
                TERM3(g3, B1h[3][3], B1l[3][3], dh, dl)
            }

            // ----- layer 1 state update -----
            {
                f32x4 hv;
#pragma unroll
                for (int r = 0; r < 4; ++r) {
                    const float iv = sigf(g0[r]), fv = sigf(g1[r]);
                    const float gv = thf(g2[r]),  ov = sigf(g3[r]);
                    c2[r] = fv * c2[r] + iv * gv;
                    hv[r] = ov * thf(c2[r]);
                }
                unsigned d0, d1, e0, e1;
                asm("v_cvt_pk_bf16_f32 %0, %1, %2" : "=v"(d0) : "v"(hv[0]), "v"(hv[1]));
                asm("v_cvt_pk_bf16_f32 %0, %1, %2" : "=v"(d1) : "v"(hv[2]), "v"(hv[3]));
                const float p0 = __uint_as_float(d0 << 16);
                const float p1 = __uint_as_float(d0 & 0xFFFF0000u);
                const float p2 = __uint_as_float(d1 << 16);
                const float p3 = __uint_as_float(d1 & 0xFFFF0000u);
                asm("v_cvt_pk_bf16_f32 %0, %1, %2" : "=v"(e0) : "v"(hv[0] - p0), "v"(hv[1] - p1));
                asm("v_cvt_pk_bf16_f32 %0, %1, %2" : "=v"(e1) : "v"(hv[2] - p2), "v"(hv[3] - p3));
                *(uint2*)&h2_hi[col][ub] = make_uint2(d0, d1);
                *(uint2*)&h2_lo[col][ub] = make_uint2(e0, e1);
            }
            __syncthreads();
        }
    }

    // ---------------- FC head on final h2 ----------------
    if (tid < NS * 4) {
        const int s = tid >> 2, k = tid & 3;
        float a = fc_b[k];
#pragma unroll
        for (int j = 0; j < HH; ++j) {
            const float hvv = bf2f((unsigned short)h2_hi[s][j]) + bf2f((unsigned short)h2_lo[s][j]);
            a = fmaf(hvv, fc_w[k * HH + j], a);
        }
        out[(size_t)(s0 + s) * 4 + k] = a;
    }
}

extern "C" void kernel_launch(void* const* d_in, const int* in_sizes, int n_in,
                              void* d_out, int out_size, void* d_ws, size_t ws_size,
                              hipStream_t stream) {
    const float* x     = (const float*)d_in[0];
    const float* w_ih0 = (const float*)d_in[1];
    const float* w_hh0 = (const float*)d_in[2];
    const float* b_ih0 = (const float*)d_in[3];
    const float* b_hh0 = (const float*)d_in[4];
    const float* w_ih1 = (const float*)d_in[5];
    const float* w_hh1 = (const float*)d_in[6];
    const float* b_ih1 = (const float*)d_in[7];
    const float* b_hh1 = (const float*)d_in[8];
    const float* fc_w  = (const float*)d_in[9];
    const float* fc_b  = (const float*)d_in[10];
    float* out = (float*)d_out;

    dim3 grid(BB / NS), block(256);
    weather_lstm_mfma<<<grid, block, 0, stream>>>(
        x, w_ih0, w_hh0, b_ih0, b_hh0,
        w_ih1, w_hh1, b_ih1, b_hh1, fc_w, fc_b, out);
}

// Round 6
// 516.555 us; speedup vs baseline: 345.0022x; 1.0123x over previous
//
#include <hip/hip_runtime.h>

#define TT 168
#define HH 64
#define DD 7
#define NS 32      // samples per block: 2 N=16 MFMA sample-tiles
#define BB 8192
#define CH 8       // timesteps per staged x chunk
#define NCH 21     // 168/8 exactly, no tail

typedef float f32x4 __attribute__((ext_vector_type(4)));
typedef short bf16x8 __attribute__((ext_vector_type(8)));

#define MFMA16(A, B, C) __builtin_amdgcn_mfma_f32_16x16x32_bf16((A), (B), (C), 0, 0, 0)

// (Wh+Wl)*(Dh+Dl) ~= Wh*Dh + Wl*Dh + Wh*Dl
#define TERM3(G, Wh, Wl, Dh, Dl)  \
    G = MFMA16(Wh, Dh, G);        \
    G = MFMA16(Wl, Dh, G);        \
    G = MFMA16(Wh, Dl, G);

__device__ __forceinline__ unsigned short bf16r(float v) {   // RTNE bf16
    union { float f; unsigned u; } x; x.f = v;
    unsigned r = x.u + 0x7FFFu + ((x.u >> 16) & 1u);
    return (unsigned short)(r >> 16);
}
__device__ __forceinline__ float bf2f(unsigned short h) {
    union { unsigned u; float f; } x; x.u = ((unsigned)h) << 16; return x.f;
}
__device__ __forceinline__ void split8(f32x4 a, f32x4 b, bf16x8& hi, bf16x8& lo) {
#pragma unroll
    for (int e = 0; e < 4; ++e) {
        unsigned short h = bf16r(a[e]);
        hi[e] = (short)h;
        lo[e] = (short)bf16r(a[e] - bf2f(h));
    }
#pragma unroll
    for (int e = 0; e < 4; ++e) {
        unsigned short h = bf16r(b[e]);
        hi[4 + e] = (short)h;
        lo[4 + e] = (short)bf16r(b[e] - bf2f(h));
    }
}

// fast activations: v_exp_f32 + v_rcp_f32, saturation-safe
__device__ __forceinline__ float sigf(float v) {
    return __builtin_amdgcn_rcpf(1.0f + __builtin_amdgcn_exp2f(v * -1.44269504f));
}
__device__ __forceinline__ float thf(float v) {
    return fmaf(-2.0f, __builtin_amdgcn_rcpf(__builtin_amdgcn_exp2f(v * 2.88539008f) + 1.0f), 1.0f);
}

__global__ __launch_bounds__(256, 1)
void weather_lstm_mfma(const float* __restrict__ x,
                       const float* __restrict__ w_ih0, const float* __restrict__ w_hh0,
                       const float* __restrict__ b_ih0, const float* __restrict__ b_hh0,
                       const float* __restrict__ w_ih1, const float* __restrict__ w_hh1,
                       const float* __restrict__ b_ih1, const float* __restrict__ b_hh1,
                       const float* __restrict__ fc_w, const float* __restrict__ fc_b,
                       float* __restrict__ out)
{
    __shared__ bf16x8 xs_hi[2][CH][NS];               // 8 KB
    __shared__ bf16x8 xs_lo[2][CH][NS];               // 8 KB
    __shared__ __align__(16) short h1_hi[NS][72], h1_lo[NS][72];   // 9.2 KB
    __shared__ __align__(16) short h2_hi[NS][72], h2_lo[NS][72];   // 9.2 KB

    const int tid  = threadIdx.x;
    const int q    = tid >> 6;       // wave = unit group (units 16q..16q+15)
    const int lane = tid & 63;
    const int col  = lane & 15;      // weight row within tile / sample within stile
    const int kg   = lane >> 4;      // k-group
    const int s0   = blockIdx.x * NS;

    // ---------------- stationary weight fragments (A-operand) ----------------
    bf16x8 B0h[4][2], B0l[4][2];   // w_hh0  (K=64)
    bf16x8 BXh[4],    BXl[4];      // w_ih0 + bias0 in k-slot 7 (kg==0 only)
    bf16x8 B1h[4][4], B1l[4][4];   // kf 0..1: w_ih1 (h1-input); kf 2..3: w_hh1 (h2-input)
    f32x4 bias1[4];
#pragma unroll
    for (int t4 = 0; t4 < 4; ++t4) {
        const int row = 64 * t4 + 16 * q + col;
        const int rr  = 64 * t4 + 16 * q + 4 * kg;
        bias1[t4] = *(const f32x4*)(b_ih1 + rr) + *(const f32x4*)(b_hh1 + rr);
#pragma unroll
        for (int kf = 0; kf < 2; ++kf) {
            const float* p = w_hh0 + (size_t)row * HH + 32 * kf + 8 * kg;
            split8(*(const f32x4*)p, *(const f32x4*)(p + 4), B0h[t4][kf], B0l[t4][kf]);
        }
#pragma unroll
        for (int kf = 0; kf < 4; ++kf) {
            const float* base = (kf < 2) ? (w_ih1 + (size_t)row * HH + 32 * kf)
                                         : (w_hh1 + (size_t)row * HH + 32 * (kf - 2));
            const float* p = base + 8 * kg;
            split8(*(const f32x4*)p, *(const f32x4*)(p + 4), B1h[t4][kf], B1l[t4][kf]);
        }
        {
            f32x4 a = {0, 0, 0, 0}, b = {0, 0, 0, 0};
            if (kg == 0) {
                const float* p = w_ih0 + (size_t)row * DD;
                a[0] = p[0]; a[1] = p[1]; a[2] = p[2]; a[3] = p[3];
                b[0] = p[4]; b[1] = p[5]; b[2] = p[6];
                b[3] = b_ih0[row] + b_hh0[row];     // bias0 rides k-slot 7 (x=1 there)
            }
            split8(a, b, BXh[t4], BXl[t4]);
        }
    }

    // ---------------- init: zero h, stage chunk 0 ----------------
    for (int i = tid; i < NS * 72; i += 256) {
        ((short*)h1_hi)[i] = 0; ((short*)h1_lo)[i] = 0;
        ((short*)h2_hi)[i] = 0; ((short*)h2_lo)[i] = 0;
    }
    {
        const int tloc = tid >> 5, ss = tid & 31;    // 8 steps x 32 samples = 256
        const float* px = x + ((size_t)(s0 + ss) * TT + tloc) * DD;
        f32x4 a, b;
        a[0] = px[0]; a[1] = px[1]; a[2] = px[2]; a[3] = px[3];
        b[0] = px[4]; b[1] = px[5]; b[2] = px[6]; b[3] = 1.0f;   // bias slot
        bf16x8 hi, lo; split8(a, b, hi, lo);
        xs_hi[0][tloc][ss] = hi; xs_lo[0][tloc][ss] = lo;
    }

    const bf16x8 z8 = {0, 0, 0, 0, 0, 0, 0, 0};
    f32x4 c1[2] = {{0,0,0,0},{0,0,0,0}}, c2[2] = {{0,0,0,0},{0,0,0,0}};
    const int ub = 16 * q + 4 * kg;          // base unit this lane updates

    __syncthreads();

#pragma unroll 1
    for (int c = 0; c < NCH; ++c) {
        const int buf = c & 1;
        if (c + 1 < NCH) {                   // prefetch next x chunk
            const int tloc = tid >> 5, ss = tid & 31;
            const int tg = (c + 1) * CH + tloc;
            const float* px = x + ((size_t)(s0 + ss) * TT + tg) * DD;
            f32x4 a, b;
            a[0] = px[0]; a[1] = px[1]; a[2] = px[2]; a[3] = px[3];
            b[0] = px[4]; b[1] = px[5]; b[2] = px[6]; b[3] = 1.0f;
            bf16x8 hi, lo; split8(a, b, hi, lo);
            xs_hi[buf ^ 1][tloc][ss] = hi; xs_lo[buf ^ 1][tloc][ss] = lo;
        }

#pragma unroll 1
        for (int tt = 0; tt < CH; ++tt) {
            f32x4 aA[2][4], aB[2][4];
#pragma unroll
            for (int st = 0; st < 2; ++st)
#pragma unroll
                for (int t4 = 0; t4 < 4; ++t4) {
                    aA[st][t4] = (f32x4){0, 0, 0, 0};   // bias0 comes via MFMA
                    aB[st][t4] = bias1[t4];
                }

            // ----- phase A: L0 gates (x + h1(t-1)) ; phase B hoisted: L1 h2(t-1) part -----
#pragma unroll
            for (int st = 0; st < 2; ++st) {
                bf16x8 axh = z8, axl = z8;
                if (kg == 0) { axh = xs_hi[buf][tt][16 * st + col]; axl = xs_lo[buf][tt][16 * st + col]; }
                TERM3(aA[st][0], BXh[0], BXl[0], axh, axl)
                TERM3(aA[st][1], BXh[1], BXl[1], axh, axl)
                TERM3(aA[st][2], BXh[2], BXl[2], axh, axl)
                TERM3(aA[st][3], BXh[3], BXl[3], axh, axl)
#pragma unroll
                for (int kf = 0; kf < 2; ++kf) {
                    const bf16x8 dh = *(const bf16x8*)&h1_hi[16 * st + col][32 * kf + 8 * kg];
                    const bf16x8 dl = *(const bf16x8*)&h1_lo[16 * st + col][32 * kf + 8 * kg];
                    TERM3(aA[st][0], B0h[0][kf], B0l[0][kf], dh, dl)
                    TERM3(aA[st][1], B0h[1][kf], B0l[1][kf], dh, dl)
                    TERM3(aA[st][2], B0h[2][kf], B0l[2][kf], dh, dl)
                    TERM3(aA[st][3], B0h[3][kf], B0l[3][kf], dh, dl)
                }
#pragma unroll
                for (int kf = 0; kf < 2; ++kf) {
                    const bf16x8 eh = *(const bf16x8*)&h2_hi[16 * st + col][32 * kf + 8 * kg];
                    const bf16x8 el = *(const bf16x8*)&h2_lo[16 * st + col][32 * kf + 8 * kg];
                    TERM3(aB[st][0], B1h[0][kf + 2], B1l[0][kf + 2], eh, el)
                    TERM3(aB[st][1], B1h[1][kf + 2], B1l[1][kf + 2], eh, el)
                    TERM3(aB[st][2], B1h[2][kf + 2], B1l[2][kf + 2], eh, el)
                    TERM3(aB[st][3], B1h[3][kf + 2], B1l[3][kf + 2], eh, el)
                }
            }

            // ----- L0 state update: units ub..ub+3, samples 16*st+col -----
#pragma unroll
            for (int st = 0; st < 2; ++st) {
                f32x4 hv;
#pragma unroll
                for (int r = 0; r < 4; ++r) {
                    const float iv = sigf(aA[st][0][r]), fv = sigf(aA[st][1][r]);
                    const float gv = thf(aA[st][2][r]),  ov = sigf(aA[st][3][r]);
                    c1[st][r] = fv * c1[st][r] + iv * gv;
                    hv[r] = ov * thf(c1[st][r]);
                }
                unsigned d0, d1, e0, e1;
                asm("v_cvt_pk_bf16_f32 %0, %1, %2" : "=v"(d0) : "v"(hv[0]), "v"(hv[1]));
                asm("v_cvt_pk_bf16_f32 %0, %1, %2" : "=v"(d1) : "v"(hv[2]), "v"(hv[3]));
                const float p0 = __uint_as_float(d0 << 16);
                const float p1 = __uint_as_float(d0 & 0xFFFF0000u);
                const float p2 = __uint_as_float(d1 << 16);
                const float p3 = __uint_as_float(d1 & 0xFFFF0000u);
                asm("v_cvt_pk_bf16_f32 %0, %1, %2" : "=v"(e0) : "v"(hv[0] - p0), "v"(hv[1] - p1));
                asm("v_cvt_pk_bf16_f32 %0, %1, %2" : "=v"(e1) : "v"(hv[2] - p2), "v"(hv[3] - p3));
                *(uint2*)&h1_hi[16 * st + col][ub] = make_uint2(d0, d1);
                *(uint2*)&h1_lo[16 * st + col][ub] = make_uint2(e0, e1);
            }
            __syncthreads();

            // ----- phase D: L1 h1(t) part -----
#pragma unroll
            for (int st = 0; st < 2; ++st) {
#pragma unroll
                for (int kf = 0; kf < 2; ++kf) {
                    const bf16x8 dh = *(const bf16x8*)&h1_hi[16 * st + col][32 * kf + 8 * kg];
                    const bf16x8 dl = *(const bf16x8*)&h1_lo[16 * st + col][32 * kf + 8 * kg];
                    TERM3(aB[st][0], B1h[0][kf], B1l[0][kf], dh, dl)
                    TERM3(aB[st][1], B1h[1][kf], B1l[1][kf], dh, dl)
                    TERM3(aB[st][2], B1h[2][kf], B1l[2][kf], dh, dl)
                    TERM3(aB[st][3], B1h[3][kf], B1l[3][kf], dh, dl)
                }
            }

            // ----- L1 state update -----
#pragma unroll
            for (int st = 0; st < 2; ++st) {
                f32x4 hv;
#pragma unroll
                for (int r = 0; r < 4; ++r) {
                    const float iv = sigf(aB[st][0][r]), fv = sigf(aB[st][1][r]);
                    const float gv = thf(aB[st][2][r]),  ov = sigf(aB[st][3][r]);
                    c2[st][r] = fv * c2[st][r] + iv * gv;
                    hv[r] = ov * thf(c2[st][r]);
                }
                unsigned d0, d1, e0, e1;
                asm("v_cvt_pk_bf16_f32 %0, %1, %2" : "=v"(d0) : "v"(hv[0]), "v"(hv[1]));
                asm("v_cvt_pk_bf16_f32 %0, %1, %2" : "=v"(d1) : "v"(hv[2]), "v"(hv[3]));
                const float p0 = __uint_as_float(d0 << 16);
                const float p1 = __uint_as_float(d0 & 0xFFFF0000u);
                const float p2 = __uint_as_float(d1 << 16);
                const float p3 = __uint_as_float(d1 & 0xFFFF0000u);
                asm("v_cvt_pk_bf16_f32 %0, %1, %2" : "=v"(e0) : "v"(hv[0] - p0), "v"(hv[1] - p1));
                asm("v_cvt_pk_bf16_f32 %0, %1, %2" : "=v"(e1) : "v"(hv[2] - p2), "v"(hv[3] - p3));
                *(uint2*)&h2_hi[16 * st + col][ub] = make_uint2(d0, d1);
                *(uint2*)&h2_lo[16 * st + col][ub] = make_uint2(e0, e1);
            }
            __syncthreads();
        }
    }

    // ---------------- FC head on final h2 ----------------
    if (tid < NS * 4) {
        const int s = tid >> 2, k = tid & 3;
        float a = fc_b[k];
#pragma unroll
        for (int j = 0; j < HH; ++j) {
            const float hvv = bf2f((unsigned short)h2_hi[s][j]) + bf2f((unsigned short)h2_lo[s][j]);
            a = fmaf(hvv, fc_w[k * HH + j], a);
        }
        out[(size_t)(s0 + s) * 4 + k] = a;
    }
}

extern "C" void kernel_launch(void* const* d_in, const int* in_sizes, int n_in,
                              void* d_out, int out_size, void* d_ws, size_t ws_size,
                              hipStream_t stream) {
    const float* x     = (const float*)d_in[0];
    const float* w_ih0 = (const float*)d_in[1];
    const float* w_hh0 = (const float*)d_in[2];
    const float* b_ih0 = (const float*)d_in[3];
    const float* b_hh0 = (const float*)d_in[4];
    const float* w_ih1 = (const float*)d_in[5];
    const float* w_hh1 = (const float*)d_in[6];
    const float* b_ih1 = (const float*)d_in[7];
    const float* b_hh1 = (const float*)d_in[8];
    const float* fc_w  = (const float*)d_in[9];
    const float* fc_b  = (const float*)d_in[10];
    float* out = (float*)d_out;

    dim3 grid(BB / NS), block(256);
    weather_lstm_mfma<<<grid, block, 0, stream>>>(
        x, w_ih0, w_hh0, b_ih0, b_hh0,
        w_ih1, w_hh1, b_ih1, b_hh1, fc_w, fc_b, out);
}

// Round 7
// 385.840 us; speedup vs baseline: 461.8818x; 1.3388x over previous
//
#include <hip/hip_runtime.h>

#define TT 168
#define HH 64
#define DD 7
#define NS 32      // samples per block: 2 N=16 MFMA sample-tiles
#define BB 8192
#define CH 8       // timesteps per staged x chunk
#define NTH 512    // waves 0-3: layer0 engine; waves 4-7: layer1 engine

typedef float f32x4 __attribute__((ext_vector_type(4)));
typedef short bf16x8 __attribute__((ext_vector_type(8)));

#define MFMA16(A, B, C) __builtin_amdgcn_mfma_f32_16x16x32_bf16((A), (B), (C), 0, 0, 0)

// (Wh+Wl)*(Dh+Dl) ~= Wh*Dh + Wl*Dh + Wh*Dl
#define TERM3(G, Wh, Wl, Dh, Dl)  \
    G = MFMA16(Wh, Dh, G);        \
    G = MFMA16(Wl, Dh, G);        \
    G = MFMA16(Wh, Dl, G);

__device__ __forceinline__ unsigned short bf16r(float v) {   // RTNE bf16
    union { float f; unsigned u; } x; x.f = v;
    unsigned r = x.u + 0x7FFFu + ((x.u >> 16) & 1u);
    return (unsigned short)(r >> 16);
}
__device__ __forceinline__ float bf2f(unsigned short h) {
    union { unsigned u; float f; } x; x.u = ((unsigned)h) << 16; return x.f;
}
__device__ __forceinline__ void split8(f32x4 a, f32x4 b, bf16x8& hi, bf16x8& lo) {
#pragma unroll
    for (int e = 0; e < 4; ++e) {
        unsigned short h = bf16r(a[e]);
        hi[e] = (short)h;
        lo[e] = (short)bf16r(a[e] - bf2f(h));
    }
#pragma unroll
    for (int e = 0; e < 4; ++e) {
        unsigned short h = bf16r(b[e]);
        hi[4 + e] = (short)h;
        lo[4 + e] = (short)bf16r(b[e] - bf2f(h));
    }
}

// fast activations: v_exp_f32 + v_rcp_f32, saturation-safe
__device__ __forceinline__ float sigf(float v) {
    return __builtin_amdgcn_rcpf(1.0f + __builtin_amdgcn_exp2f(v * -1.44269504f));
}
__device__ __forceinline__ float thf(float v) {
    return fmaf(-2.0f, __builtin_amdgcn_rcpf(__builtin_amdgcn_exp2f(v * 2.88539008f) + 1.0f), 1.0f);
}

// cell update + split-precision writeback of h (4 units, 1 sample) to LDS
__device__ __forceinline__ void cell_update(const f32x4& gi, const f32x4& gf,
                                            const f32x4& gg, const f32x4& go,
                                            f32x4& cst, short* dst_hi, short* dst_lo) {
    f32x4 hv;
#pragma unroll
    for (int r = 0; r < 4; ++r) {
        const float iv = sigf(gi[r]), fv = sigf(gf[r]);
        const float gv = thf(gg[r]),  ov = sigf(go[r]);
        cst[r] = fv * cst[r] + iv * gv;
        hv[r] = ov * thf(cst[r]);
    }
    unsigned d0, d1, e0, e1;
    asm("v_cvt_pk_bf16_f32 %0, %1, %2" : "=v"(d0) : "v"(hv[0]), "v"(hv[1]));
    asm("v_cvt_pk_bf16_f32 %0, %1, %2" : "=v"(d1) : "v"(hv[2]), "v"(hv[3]));
    const float p0 = __uint_as_float(d0 << 16);
    const float p1 = __uint_as_float(d0 & 0xFFFF0000u);
    const float p2 = __uint_as_float(d1 << 16);
    const float p3 = __uint_as_float(d1 & 0xFFFF0000u);
    asm("v_cvt_pk_bf16_f32 %0, %1, %2" : "=v"(e0) : "v"(hv[0] - p0), "v"(hv[1] - p1));
    asm("v_cvt_pk_bf16_f32 %0, %1, %2" : "=v"(e1) : "v"(hv[2] - p2), "v"(hv[3] - p3));
    *(uint2*)dst_hi = make_uint2(d0, d1);
    *(uint2*)dst_lo = make_uint2(e0, e1);
}

__global__ __launch_bounds__(NTH, 2)
void weather_lstm_mfma(const float* __restrict__ x,
                       const float* __restrict__ w_ih0, const float* __restrict__ w_hh0,
                       const float* __restrict__ b_ih0, const float* __restrict__ b_hh0,
                       const float* __restrict__ w_ih1, const float* __restrict__ w_hh1,
                       const float* __restrict__ b_ih1, const float* __restrict__ b_hh1,
                       const float* __restrict__ fc_w, const float* __restrict__ fc_b,
                       float* __restrict__ out)
{
    __shared__ bf16x8 xs_hi[2][CH][NS];                    // 8 KB
    __shared__ bf16x8 xs_lo[2][CH][NS];                    // 8 KB
    __shared__ __align__(16) short h1_hi[2][NS][72], h1_lo[2][NS][72];  // 18.4 KB
    __shared__ __align__(16) short h2_hi[2][NS][72], h2_lo[2][NS][72];  // 18.4 KB

    const int tid  = threadIdx.x;
    const int wv   = tid >> 6;       // 0..7
    const int q    = wv & 3;         // unit group within the engine
    const int lane = tid & 63;
    const int col  = lane & 15;      // weight row within tile / sample within stile
    const int kg   = lane >> 4;      // k-group
    const int s0   = blockIdx.x * NS;
    const int ub   = 16 * q + 4 * kg;

    // ---------------- init: zero h (both parities), stage x chunk 0 ----------------
    for (int i = tid; i < 2 * NS * 72; i += NTH) {
        ((short*)h1_hi)[i] = 0; ((short*)h1_lo)[i] = 0;
        ((short*)h2_hi)[i] = 0; ((short*)h2_lo)[i] = 0;
    }
    if (tid < 256) {
        const int tloc = tid >> 5, ss = tid & 31;
        const float* px = x + ((size_t)(s0 + ss) * TT + tloc) * DD;
        f32x4 a, b;
        a[0] = px[0]; a[1] = px[1]; a[2] = px[2]; a[3] = px[3];
        b[0] = px[4]; b[1] = px[5]; b[2] = px[6]; b[3] = 1.0f;   // bias slot
        bf16x8 hi, lo; split8(a, b, hi, lo);
        xs_hi[0][tloc][ss] = hi; xs_lo[0][tloc][ss] = lo;
    }
    __syncthreads();

    const bf16x8 z8 = {0, 0, 0, 0, 0, 0, 0, 0};

    if (wv < 4) {
        // ==================== LAYER-0 ENGINE (waves 0-3) ====================
        bf16x8 W0h[4][2], W0l[4][2];   // w_hh0 (K=64)
        bf16x8 WXh[4],    WXl[4];      // w_ih0 + bias0 in k-slot 7
#pragma unroll
        for (int t4 = 0; t4 < 4; ++t4) {
            const int row = 64 * t4 + 16 * q + col;
#pragma unroll
            for (int kf = 0; kf < 2; ++kf) {
                const float* p = w_hh0 + (size_t)row * HH + 32 * kf + 8 * kg;
                split8(*(const f32x4*)p, *(const f32x4*)(p + 4), W0h[t4][kf], W0l[t4][kf]);
            }
            f32x4 a = {0, 0, 0, 0}, b = {0, 0, 0, 0};
            if (kg == 0) {
                const float* p = w_ih0 + (size_t)row * DD;
                a[0] = p[0]; a[1] = p[1]; a[2] = p[2]; a[3] = p[3];
                b[0] = p[4]; b[1] = p[5]; b[2] = p[6];
                b[3] = b_ih0[row] + b_hh0[row];     // bias0 rides k-slot 7
            }
            split8(a, b, WXh[t4], WXl[t4]);
        }
        f32x4 c1[2] = {{0,0,0,0},{0,0,0,0}};

#pragma unroll 1
        for (int k = 0; k <= TT; ++k) {
            const int p = k & 1;
            if (k < TT) {
                // refill next x chunk at chunk boundaries
                if ((k & 7) == 0 && k + CH < TT) {
                    const int tloc = (tid & 255) >> 5, ss = tid & 31;
                    const int tg = k + CH + tloc;
                    const float* px = x + ((size_t)(s0 + ss) * TT + tg) * DD;
                    f32x4 a, b;
                    a[0] = px[0]; a[1] = px[1]; a[2] = px[2]; a[3] = px[3];
                    b[0] = px[4]; b[1] = px[5]; b[2] = px[6]; b[3] = 1.0f;
                    bf16x8 hi, lo; split8(a, b, hi, lo);
                    const int nb = ((k >> 3) & 1) ^ 1;
                    xs_hi[nb][tloc][ss] = hi; xs_lo[nb][tloc][ss] = lo;
                }
                const int cb = (k >> 3) & 1, tt = k & 7;

                f32x4 aA[2][4];
#pragma unroll
                for (int st = 0; st < 2; ++st)
#pragma unroll
                    for (int t4 = 0; t4 < 4; ++t4) aA[st][t4] = (f32x4){0, 0, 0, 0};

#pragma unroll
                for (int st = 0; st < 2; ++st) {
                    bf16x8 axh = z8, axl = z8;
                    if (kg == 0) { axh = xs_hi[cb][tt][16 * st + col]; axl = xs_lo[cb][tt][16 * st + col]; }
                    TERM3(aA[st][0], WXh[0], WXl[0], axh, axl)
                    TERM3(aA[st][1], WXh[1], WXl[1], axh, axl)
                    TERM3(aA[st][2], WXh[2], WXl[2], axh, axl)
                    TERM3(aA[st][3], WXh[3], WXl[3], axh, axl)
#pragma unroll
                    for (int kf = 0; kf < 2; ++kf) {
                        const bf16x8 dh = *(const bf16x8*)&h1_hi[p][16 * st + col][32 * kf + 8 * kg];
                        const bf16x8 dl = *(const bf16x8*)&h1_lo[p][16 * st + col][32 * kf + 8 * kg];
                        TERM3(aA[st][0], W0h[0][kf], W0l[0][kf], dh, dl)
                        TERM3(aA[st][1], W0h[1][kf], W0l[1][kf], dh, dl)
                        TERM3(aA[st][2], W0h[2][kf], W0l[2][kf], dh, dl)
                        TERM3(aA[st][3], W0h[3][kf], W0l[3][kf], dh, dl)
                    }
                }
#pragma unroll
                for (int st = 0; st < 2; ++st)
                    cell_update(aA[st][0], aA[st][1], aA[st][2], aA[st][3], c1[st],
                                &h1_hi[p ^ 1][16 * st + col][ub], &h1_lo[p ^ 1][16 * st + col][ub]);
            }
            __syncthreads();
        }
    } else {
        // ==================== LAYER-1 ENGINE (waves 4-7) ====================
        bf16x8 W1h[4][4], W1l[4][4];   // kf 0..1: w_ih1 (h1 input); kf 2..3: w_hh1 (h2 input)
        f32x4 bias1[4];
#pragma unroll
        for (int t4 = 0; t4 < 4; ++t4) {
            const int row = 64 * t4 + 16 * q + col;
            const int rr  = 64 * t4 + 16 * q + 4 * kg;
            bias1[t4] = *(const f32x4*)(b_ih1 + rr) + *(const f32x4*)(b_hh1 + rr);
#pragma unroll
            for (int kf = 0; kf < 4; ++kf) {
                const float* base = (kf < 2) ? (w_ih1 + (size_t)row * HH + 32 * kf)
                                             : (w_hh1 + (size_t)row * HH + 32 * (kf - 2));
                const float* p = base + 8 * kg;
                split8(*(const f32x4*)p, *(const f32x4*)(p + 4), W1h[t4][kf], W1l[t4][kf]);
            }
        }
        f32x4 c2[2] = {{0,0,0,0},{0,0,0,0}};

#pragma unroll 1
        for (int k = 0; k <= TT; ++k) {
            const int p = k & 1;
            if (k >= 1) {
                f32x4 aB[2][4];
#pragma unroll
                for (int st = 0; st < 2; ++st)
#pragma unroll
                    for (int t4 = 0; t4 < 4; ++t4) aB[st][t4] = bias1[t4];

#pragma unroll
                for (int st = 0; st < 2; ++st) {
#pragma unroll
                    for (int kf = 0; kf < 2; ++kf) {   // h1(k-1) input
                        const bf16x8 dh = *(const bf16x8*)&h1_hi[p][16 * st + col][32 * kf + 8 * kg];
                        const bf16x8 dl = *(const bf16x8*)&h1_lo[p][16 * st + col][32 * kf + 8 * kg];
                        TERM3(aB[st][0], W1h[0][kf], W1l[0][kf], dh, dl)
                        TERM3(aB[st][1], W1h[1][kf], W1l[1][kf], dh, dl)
                        TERM3(aB[st][2], W1h[2][kf], W1l[2][kf], dh, dl)
                        TERM3(aB[st][3], W1h[3][kf], W1l[3][kf], dh, dl)
                    }
#pragma unroll
                    for (int kf = 0; kf < 2; ++kf) {   // h2(k-2) input
                        const bf16x8 eh = *(const bf16x8*)&h2_hi[p][16 * st + col][32 * kf + 8 * kg];
                        const bf16x8 el = *(const bf16x8*)&h2_lo[p][16 * st + col][32 * kf + 8 * kg];
                        TERM3(aB[st][0], W1h[0][kf + 2], W1l[0][kf + 2], eh, el)
                        TERM3(aB[st][1], W1h[1][kf + 2], W1l[1][kf + 2], eh, el)
                        TERM3(aB[st][2], W1h[2][kf + 2], W1l[2][kf + 2], eh, el)
                        TERM3(aB[st][3], W1h[3][kf + 2], W1l[3][kf + 2], eh, el)
                    }
                }
#pragma unroll
                for (int st = 0; st < 2; ++st)
                    cell_update(aB[st][0], aB[st][1], aB[st][2], aB[st][3], c2[st],
                                &h2_hi[p ^ 1][16 * st + col][ub], &h2_lo[p ^ 1][16 * st + col][ub]);
            }
            __syncthreads();
        }
    }

    // ---------------- FC head on final h2 (= h2(TT-1), parity 1) ----------------
    if (tid < NS * 4) {
        const int s = tid >> 2, k = tid & 3;
        float a = fc_b[k];
#pragma unroll
        for (int j = 0; j < HH; ++j) {
            const float hvv = bf2f((unsigned short)h2_hi[1][s][j]) + bf2f((unsigned short)h2_lo[1][s][j]);
            a = fmaf(hvv, fc_w[k * HH + j], a);
        }
        out[(size_t)(s0 + s) * 4 + k] = a;
    }
}

extern "C" void kernel_launch(void* const* d_in, const int* in_sizes, int n_in,
                              void* d_out, int out_size, void* d_ws, size_t ws_size,
                              hipStream_t stream) {
    const float* x     = (const float*)d_in[0];
    const float* w_ih0 = (const float*)d_in[1];
    const float* w_hh0 = (const float*)d_in[2];
    const float* b_ih0 = (const float*)d_in[3];
    const float* b_hh0 = (const float*)d_in[4];
    const float* w_ih1 = (const float*)d_in[5];
    const float* w_hh1 = (const float*)d_in[6];
    const float* b_ih1 = (const float*)d_in[7];
    const float* b_hh1 = (const float*)d_in[8];
    const float* fc_w  = (const float*)d_in[9];
    const float* fc_b  = (const float*)d_in[10];
    float* out = (float*)d_out;

    dim3 grid(BB / NS), block(NTH);
    weather_lstm_mfma<<<grid, block, 0, stream>>>(
        x, w_ih0, w_hh0, b_ih0, b_hh0,
        w_ih1, w_hh1, b_ih1, b_hh1, fc_w, fc_b, out);
}

// Round 8
// 379.744 us; speedup vs baseline: 469.2969x; 1.0161x over previous
//
#include <hip/hip_runtime.h>

#define TT 168
#define HH 64
#define DD 7
#define NS 32      // samples per block: 2 N=16 MFMA sample-tiles
#define BB 8192
#define CH 8       // timesteps per staged x chunk
#define NTH 512    // waves 0-3: layer0 engine; waves 4-7: layer1 engine

typedef float f32x4 __attribute__((ext_vector_type(4)));
typedef short bf16x8 __attribute__((ext_vector_type(8)));

#define MFMA16(A, B, C) __builtin_amdgcn_mfma_f32_16x16x32_bf16((A), (B), (C), 0, 0, 0)

// (Wh+Wl)*(Dh+Dl) ~= Wh*Dh + Wl*Dh + Wh*Dl
#define TERM3(G, Wh, Wl, Dh, Dl)  \
    G = MFMA16(Wh, Dh, G);        \
    G = MFMA16(Wl, Dh, G);        \
    G = MFMA16(Wh, Dl, G);

__device__ __forceinline__ unsigned short bf16r(float v) {   // RTNE bf16
    union { float f; unsigned u; } x; x.f = v;
    unsigned r = x.u + 0x7FFFu + ((x.u >> 16) & 1u);
    return (unsigned short)(r >> 16);
}
__device__ __forceinline__ float bf2f(unsigned short h) {
    union { unsigned u; float f; } x; x.u = ((unsigned)h) << 16; return x.f;
}
__device__ __forceinline__ void split8(f32x4 a, f32x4 b, bf16x8& hi, bf16x8& lo) {
#pragma unroll
    for (int e = 0; e < 4; ++e) {
        unsigned short h = bf16r(a[e]);
        hi[e] = (short)h;
        lo[e] = (short)bf16r(a[e] - bf2f(h));
    }
#pragma unroll
    for (int e = 0; e < 4; ++e) {
        unsigned short h = bf16r(b[e]);
        hi[4 + e] = (short)h;
        lo[4 + e] = (short)bf16r(b[e] - bf2f(h));
    }
}

// fast activations: v_exp_f32 + v_rcp_f32, saturation-safe
__device__ __forceinline__ float sigf(float v) {
    return __builtin_amdgcn_rcpf(1.0f + __builtin_amdgcn_exp2f(v * -1.44269504f));
}
__device__ __forceinline__ float thf(float v) {
    return fmaf(-2.0f, __builtin_amdgcn_rcpf(__builtin_amdgcn_exp2f(v * 2.88539008f) + 1.0f), 1.0f);
}

// cell update + split-precision writeback of h (4 units, 1 sample) to LDS
__device__ __forceinline__ void cell_update(const f32x4& gi, const f32x4& gf,
                                            const f32x4& gg, const f32x4& go,
                                            f32x4& cst, short* dst_hi, short* dst_lo) {
    f32x4 hv;
#pragma unroll
    for (int r = 0; r < 4; ++r) {
        const float iv = sigf(gi[r]), fv = sigf(gf[r]);
        const float gv = thf(gg[r]),  ov = sigf(go[r]);
        cst[r] = fv * cst[r] + iv * gv;
        hv[r] = ov * thf(cst[r]);
    }
    unsigned d0, d1, e0, e1;
    asm("v_cvt_pk_bf16_f32 %0, %1, %2" : "=v"(d0) : "v"(hv[0]), "v"(hv[1]));
    asm("v_cvt_pk_bf16_f32 %0, %1, %2" : "=v"(d1) : "v"(hv[2]), "v"(hv[3]));
    const float p0 = __uint_as_float(d0 << 16);
    const float p1 = __uint_as_float(d0 & 0xFFFF0000u);
    const float p2 = __uint_as_float(d1 << 16);
    const float p3 = __uint_as_float(d1 & 0xFFFF0000u);
    asm("v_cvt_pk_bf16_f32 %0, %1, %2" : "=v"(e0) : "v"(hv[0] - p0), "v"(hv[1] - p1));
    asm("v_cvt_pk_bf16_f32 %0, %1, %2" : "=v"(e1) : "v"(hv[2] - p2), "v"(hv[3] - p3));
    *(uint2*)dst_hi = make_uint2(d0, d1);
    *(uint2*)dst_lo = make_uint2(e0, e1);
}

__global__ __launch_bounds__(NTH, 2)
void weather_lstm_mfma(const float* __restrict__ x,
                       const float* __restrict__ w_ih0, const float* __restrict__ w_hh0,
                       const float* __restrict__ b_ih0, const float* __restrict__ b_hh0,
                       const float* __restrict__ w_ih1, const float* __restrict__ w_hh1,
                       const float* __restrict__ b_ih1, const float* __restrict__ b_hh1,
                       const float* __restrict__ fc_w, const float* __restrict__ fc_b,
                       float* __restrict__ out)
{
    __shared__ bf16x8 xs_hi[2][CH][NS];                    // 8 KB
    __shared__ bf16x8 xs_lo[2][CH][NS];                    // 8 KB
    __shared__ __align__(16) short h1_hi[2][NS][72], h1_lo[2][NS][72];  // 18.4 KB
    __shared__ __align__(16) short h2_hi[2][NS][72], h2_lo[2][NS][72];  // 18.4 KB

    const int tid  = threadIdx.x;
    const int wv   = tid >> 6;       // 0..7
    const int q    = wv & 3;         // unit group within the engine
    const int lane = tid & 63;
    const int col  = lane & 15;      // weight row within tile / sample within stile
    const int kg   = lane >> 4;      // k-group
    const int s0   = blockIdx.x * NS;
    const int ub   = 16 * q + 4 * kg;

    // ---------------- init: zero h (both parities), stage x chunk 0 ----------------
    for (int i = tid; i < 2 * NS * 72; i += NTH) {
        ((short*)h1_hi)[i] = 0; ((short*)h1_lo)[i] = 0;
        ((short*)h2_hi)[i] = 0; ((short*)h2_lo)[i] = 0;
    }
    if (tid < 256) {
        const int tloc = tid >> 5, ss = tid & 31;
        const float* px = x + ((size_t)(s0 + ss) * TT + tloc) * DD;
        f32x4 a, b;
        a[0] = px[0]; a[1] = px[1]; a[2] = px[2]; a[3] = px[3];
        b[0] = px[4]; b[1] = px[5]; b[2] = px[6]; b[3] = 1.0f;   // bias slot
        bf16x8 hi, lo; split8(a, b, hi, lo);
        xs_hi[0][tloc][ss] = hi; xs_lo[0][tloc][ss] = lo;
    }
    __syncthreads();

    const bf16x8 z8 = {0, 0, 0, 0, 0, 0, 0, 0};

    if (wv < 4) {
        // ==================== LAYER-0 ENGINE (waves 0-3) ====================
        bf16x8 W0h[4][2], W0l[4][2];   // w_hh0 (K=64)
        bf16x8 WXh[4],    WXl[4];      // w_ih0 + bias0 in k-slot 7
#pragma unroll
        for (int t4 = 0; t4 < 4; ++t4) {
            const int row = 64 * t4 + 16 * q + col;
#pragma unroll
            for (int kf = 0; kf < 2; ++kf) {
                const float* p = w_hh0 + (size_t)row * HH + 32 * kf + 8 * kg;
                split8(*(const f32x4*)p, *(const f32x4*)(p + 4), W0h[t4][kf], W0l[t4][kf]);
            }
            f32x4 a = {0, 0, 0, 0}, b = {0, 0, 0, 0};
            if (kg == 0) {
                const float* p = w_ih0 + (size_t)row * DD;
                a[0] = p[0]; a[1] = p[1]; a[2] = p[2]; a[3] = p[3];
                b[0] = p[4]; b[1] = p[5]; b[2] = p[6];
                b[3] = b_ih0[row] + b_hh0[row];     // bias0 rides k-slot 7
            }
            split8(a, b, WXh[t4], WXl[t4]);
        }
        f32x4 c1[2] = {{0,0,0,0},{0,0,0,0}};

#pragma unroll 1
        for (int k = 0; k <= TT + 1; ++k) {
            f32x4 aA[2][4];
            // ---------- Segment A: L0 MFMA for step k ----------
            if (k < TT) {
                if ((k & 7) == 0 && k + CH < TT) {      // refill next x chunk
                    const int tloc = (tid & 255) >> 5, ss = tid & 31;
                    const int tg = k + CH + tloc;
                    const float* px = x + ((size_t)(s0 + ss) * TT + tg) * DD;
                    f32x4 a, b;
                    a[0] = px[0]; a[1] = px[1]; a[2] = px[2]; a[3] = px[3];
                    b[0] = px[4]; b[1] = px[5]; b[2] = px[6]; b[3] = 1.0f;
                    bf16x8 hi, lo; split8(a, b, hi, lo);
                    const int nb = ((k >> 3) & 1) ^ 1;
                    xs_hi[nb][tloc][ss] = hi; xs_lo[nb][tloc][ss] = lo;
                }
                const int cb = (k >> 3) & 1, tt = k & 7;
                const int rp = (k - 1) & 1;             // h1(k-1) parity

#pragma unroll
                for (int st = 0; st < 2; ++st)
#pragma unroll
                    for (int t4 = 0; t4 < 4; ++t4) aA[st][t4] = (f32x4){0, 0, 0, 0};

                __builtin_amdgcn_s_setprio(1);
#pragma unroll
                for (int st = 0; st < 2; ++st) {
                    bf16x8 axh = z8, axl = z8;
                    if (kg == 0) { axh = xs_hi[cb][tt][16 * st + col]; axl = xs_lo[cb][tt][16 * st + col]; }
                    TERM3(aA[st][0], WXh[0], WXl[0], axh, axl)
                    TERM3(aA[st][1], WXh[1], WXl[1], axh, axl)
                    TERM3(aA[st][2], WXh[2], WXl[2], axh, axl)
                    TERM3(aA[st][3], WXh[3], WXl[3], axh, axl)
#pragma unroll
                    for (int kf = 0; kf < 2; ++kf) {
                        const bf16x8 dh = *(const bf16x8*)&h1_hi[rp][16 * st + col][32 * kf + 8 * kg];
                        const bf16x8 dl = *(const bf16x8*)&h1_lo[rp][16 * st + col][32 * kf + 8 * kg];
                        TERM3(aA[st][0], W0h[0][kf], W0l[0][kf], dh, dl)
                        TERM3(aA[st][1], W0h[1][kf], W0l[1][kf], dh, dl)
                        TERM3(aA[st][2], W0h[2][kf], W0l[2][kf], dh, dl)
                        TERM3(aA[st][3], W0h[3][kf], W0l[3][kf], dh, dl)
                    }
                }
                __builtin_amdgcn_s_setprio(0);
            }
            __syncthreads();   // B1
            // ---------- Segment B: L0 cell update for step k ----------
            if (k < TT) {
                const int wp = k & 1;
#pragma unroll
                for (int st = 0; st < 2; ++st)
                    cell_update(aA[st][0], aA[st][1], aA[st][2], aA[st][3], c1[st],
                                &h1_hi[wp][16 * st + col][ub], &h1_lo[wp][16 * st + col][ub]);
            }
            __syncthreads();   // B2
        }
    } else {
        // ==================== LAYER-1 ENGINE (waves 4-7) ====================
        bf16x8 W1h[4][4], W1l[4][4];   // kf 0..1: w_ih1 (h1 input); kf 2..3: w_hh1 (h2 input)
        f32x4 bias1[4];
#pragma unroll
        for (int t4 = 0; t4 < 4; ++t4) {
            const int row = 64 * t4 + 16 * q + col;
            const int rr  = 64 * t4 + 16 * q + 4 * kg;
            bias1[t4] = *(const f32x4*)(b_ih1 + rr) + *(const f32x4*)(b_hh1 + rr);
#pragma unroll
            for (int kf = 0; kf < 4; ++kf) {
                const float* base = (kf < 2) ? (w_ih1 + (size_t)row * HH + 32 * kf)
                                             : (w_hh1 + (size_t)row * HH + 32 * (kf - 2));
                const float* p = base + 8 * kg;
                split8(*(const f32x4*)p, *(const f32x4*)(p + 4), W1h[t4][kf], W1l[t4][kf]);
            }
        }
        f32x4 c2[2] = {{0,0,0,0},{0,0,0,0}};
        f32x4 aB[2][4];

#pragma unroll 1
        for (int k = 0; k <= TT + 1; ++k) {
            // ---------- Segment A: L1 cell update for step k-2 ----------
            if (k >= 2) {
                const int wp = k & 1;                   // (k-2)&1
#pragma unroll
                for (int st = 0; st < 2; ++st)
                    cell_update(aB[st][0], aB[st][1], aB[st][2], aB[st][3], c2[st],
                                &h2_hi[wp][16 * st + col][ub], &h2_lo[wp][16 * st + col][ub]);
            }
            __syncthreads();   // B1
            // ---------- Segment B: L1 MFMA for step k-1 ----------
            if (k >= 1 && k <= TT) {
                const int rp1 = (k - 1) & 1;            // h1(k-1) parity
                const int rp2 = k & 1;                  // h2(k-2) parity

#pragma unroll
                for (int st = 0; st < 2; ++st)
#pragma unroll
                    for (int t4 = 0; t4 < 4; ++t4) aB[st][t4] = bias1[t4];

                __builtin_amdgcn_s_setprio(1);
#pragma unroll
                for (int st = 0; st < 2; ++st) {
#pragma unroll
                    for (int kf = 0; kf < 2; ++kf) {    // h1(k-1) input
                        const bf16x8 dh = *(const bf16x8*)&h1_hi[rp1][16 * st + col][32 * kf + 8 * kg];
                        const bf16x8 dl = *(const bf16x8*)&h1_lo[rp1][16 * st + col][32 * kf + 8 * kg];
                        TERM3(aB[st][0], W1h[0][kf], W1l[0][kf], dh, dl)
                        TERM3(aB[st][1], W1h[1][kf], W1l[1][kf], dh, dl)
                        TERM3(aB[st][2], W1h[2][kf], W1l[2][kf], dh, dl)
                        TERM3(aB[st][3], W1h[3][kf], W1l[3][kf], dh, dl)
                    }
#pragma unroll
                    for (int kf = 0; kf < 2; ++kf) {    // h2(k-2) input
                        const bf16x8 eh = *(const bf16x8*)&h2_hi[rp2][16 * st + col][32 * kf + 8 * kg];
                        const bf16x8 el = *(const bf16x8*)&h2_lo[rp2][16 * st + col][32 * kf + 8 * kg];
                        TERM3(aB[st][0], W1h[0][kf + 2], W1l[0][kf + 2], eh, el)
                        TERM3(aB[st][1], W1h[1][kf + 2], W1l[1][kf + 2], eh, el)
                        TERM3(aB[st][2], W1h[2][kf + 2], W1l[2][kf + 2], eh, el)
                        TERM3(aB[st][3], W1h[3][kf + 2], W1l[3][kf + 2], eh, el)
                    }
                }
                __builtin_amdgcn_s_setprio(0);
            }
            __syncthreads();   // B2
        }
    }

    // ---------------- FC head on final h2 = h2(TT-1), parity (TT+1)&1 ----------------
    if (tid < NS * 4) {
        const int s = tid >> 2, k = tid & 3;
        const int fp = (TT + 1) & 1;
        float a = fc_b[k];
#pragma unroll
        for (int j = 0; j < HH; ++j) {
            const float hvv = bf2f((unsigned short)h2_hi[fp][s][j]) + bf2f((unsigned short)h2_lo[fp][s][j]);
            a = fmaf(hvv, fc_w[k * HH + j], a);
        }
        out[(size_t)(s0 + s) * 4 + k] = a;
    }
}

extern "C" void kernel_launch(void* const* d_in, const int* in_sizes, int n_in,
                              void* d_out, int out_size, void* d_ws, size_t ws_size,
                              hipStream_t stream) {
    const float* x     = (const float*)d_in[0];
    const float* w_ih0 = (const float*)d_in[1];
    const float* w_hh0 = (const float*)d_in[2];
    const float* b_ih0 = (const float*)d_in[3];
    const float* b_hh0 = (const float*)d_in[4];
    const float* w_ih1 = (const float*)d_in[5];
    const float* w_hh1 = (const float*)d_in[6];
    const float* b_ih1 = (const float*)d_in[7];
    const float* b_hh1 = (const float*)d_in[8];
    const float* fc_w  = (const float*)d_in[9];
    const float* fc_b  = (const float*)d_in[10];
    float* out = (float*)d_out;

    dim3 grid(BB / NS), block(NTH);
    weather_lstm_mfma<<<grid, block, 0, stream>>>(
        x, w_ih0, w_hh0, b_ih0, b_hh0,
        w_ih1, w_hh1, b_ih1, b_hh1, fc_w, fc_b, out);
}

// Round 9
// 301.730 us; speedup vs baseline: 590.6368x; 1.2586x over previous
//
#include <hip/hip_runtime.h>

#define TT 168
#define HH 64
#define DD 7
#define NS 32      // samples per block: 2 N=16 MFMA sample-tiles
#define BB 8192
#define CH 8       // timesteps per staged x chunk
#define NTH 512    // waves 0-3: layer0 engine; waves 4-7: layer1 engine

typedef float f32x4 __attribute__((ext_vector_type(4)));
typedef _Float16 f16x8 __attribute__((ext_vector_type(8)));

#define MFMA16F(A, B, C) __builtin_amdgcn_mfma_f32_16x16x32_f16((A), (B), (C), 0, 0, 0)

// weights split hi+lo fp16 (covers fp32 mantissa), data single fp16
#define TERM2(G, Wh, Wl, D)   \
    G = MFMA16F(Wh, (D), G);  \
    G = MFMA16F(Wl, (D), G);

// weight split: hi = RTNE fp16, lo = residual
__device__ __forceinline__ void wsplit8(f32x4 a, f32x4 b, f16x8& hi, f16x8& lo) {
#pragma unroll
    for (int e = 0; e < 4; ++e) {
        const _Float16 h = (_Float16)a[e];
        hi[e] = h; lo[e] = (_Float16)(a[e] - (float)h);
    }
#pragma unroll
    for (int e = 0; e < 4; ++e) {
        const _Float16 h = (_Float16)b[e];
        hi[4 + e] = h; lo[4 + e] = (_Float16)(b[e] - (float)h);
    }
}
__device__ __forceinline__ f16x8 pack8(f32x4 a, f32x4 b) {
    f16x8 r;
#pragma unroll
    for (int e = 0; e < 4; ++e) { r[e] = (_Float16)a[e]; r[4 + e] = (_Float16)b[e]; }
    return r;
}

// fast activations: v_exp_f32 + v_rcp_f32, saturation-safe
__device__ __forceinline__ float sigf(float v) {
    return __builtin_amdgcn_rcpf(1.0f + __builtin_amdgcn_exp2f(v * -1.44269504f));
}
__device__ __forceinline__ float thf(float v) {
    return fmaf(-2.0f, __builtin_amdgcn_rcpf(__builtin_amdgcn_exp2f(v * 2.88539008f) + 1.0f), 1.0f);
}

// cell update + fp16 writeback of h (4 units, 1 sample) to LDS
__device__ __forceinline__ void cell_update(const f32x4& gi, const f32x4& gf,
                                            const f32x4& gg, const f32x4& go,
                                            f32x4& cst, _Float16* dst) {
    f32x4 hv;
#pragma unroll
    for (int r = 0; r < 4; ++r) {
        const float iv = sigf(gi[r]), fv = sigf(gf[r]);
        const float gv = thf(gg[r]),  ov = sigf(go[r]);
        cst[r] = fv * cst[r] + iv * gv;
        hv[r] = ov * thf(cst[r]);
    }
    unsigned d0, d1;
    asm("v_cvt_pkrtz_f16_f32 %0, %1, %2" : "=v"(d0) : "v"(hv[0]), "v"(hv[1]));
    asm("v_cvt_pkrtz_f16_f32 %0, %1, %2" : "=v"(d1) : "v"(hv[2]), "v"(hv[3]));
    *(uint2*)dst = make_uint2(d0, d1);
}

__global__ __launch_bounds__(NTH, 2)
void weather_lstm_mfma(const float* __restrict__ x,
                       const float* __restrict__ w_ih0, const float* __restrict__ w_hh0,
                       const float* __restrict__ b_ih0, const float* __restrict__ b_hh0,
                       const float* __restrict__ w_ih1, const float* __restrict__ w_hh1,
                       const float* __restrict__ b_ih1, const float* __restrict__ b_hh1,
                       const float* __restrict__ fc_w, const float* __restrict__ fc_b,
                       float* __restrict__ out)
{
    __shared__ f16x8 xs[2][CH][NS];                           // 8 KB
    __shared__ __align__(16) _Float16 h1[2][NS][72];          // 9.2 KB (144B rows)
    __shared__ __align__(16) _Float16 h2[2][NS][72];          // 9.2 KB

    const int tid  = threadIdx.x;
    const int wv   = tid >> 6;       // 0..7
    const int q    = wv & 3;         // unit group within the engine
    const int lane = tid & 63;
    const int col  = lane & 15;      // weight row within tile / sample within stile
    const int kg   = lane >> 4;      // k-group
    const int s0   = blockIdx.x * NS;
    const int ub   = 16 * q + 4 * kg;

    // ---------------- init: zero h (both parities), stage x chunk 0 ----------------
    for (int i = tid; i < 2 * NS * 72; i += NTH) {
        ((short*)h1)[i] = 0; ((short*)h2)[i] = 0;
    }
    if (tid < 256) {
        const int tloc = tid >> 5, ss = tid & 31;
        const float* px = x + ((size_t)(s0 + ss) * TT + tloc) * DD;
        f32x4 a, b;
        a[0] = px[0]; a[1] = px[1]; a[2] = px[2]; a[3] = px[3];
        b[0] = px[4]; b[1] = px[5]; b[2] = px[6]; b[3] = 1.0f;   // bias slot
        xs[0][tloc][ss] = pack8(a, b);
    }
    __syncthreads();

    const f16x8 z8 = {0, 0, 0, 0, 0, 0, 0, 0};

    if (wv < 4) {
        // ==================== LAYER-0 ENGINE (waves 0-3) ====================
        f16x8 W0h[4][2], W0l[4][2];   // w_hh0 (K=64)
        f16x8 WXh[4],    WXl[4];      // w_ih0 + bias0 in k-slot 7
#pragma unroll
        for (int t4 = 0; t4 < 4; ++t4) {
            const int row = 64 * t4 + 16 * q + col;
#pragma unroll
            for (int kf = 0; kf < 2; ++kf) {
                const float* p = w_hh0 + (size_t)row * HH + 32 * kf + 8 * kg;
                wsplit8(*(const f32x4*)p, *(const f32x4*)(p + 4), W0h[t4][kf], W0l[t4][kf]);
            }
            f32x4 a = {0, 0, 0, 0}, b = {0, 0, 0, 0};
            if (kg == 0) {
                const float* p = w_ih0 + (size_t)row * DD;
                a[0] = p[0]; a[1] = p[1]; a[2] = p[2]; a[3] = p[3];
                b[0] = p[4]; b[1] = p[5]; b[2] = p[6];
                b[3] = b_ih0[row] + b_hh0[row];     // bias0 rides k-slot 7
            }
            wsplit8(a, b, WXh[t4], WXl[t4]);
        }
        f32x4 c1[2] = {{0,0,0,0},{0,0,0,0}};

#pragma unroll 1
        for (int k = 0; k <= TT + 1; ++k) {
            f32x4 aA[2][4];
            // ---------- Segment A: L0 MFMA for step k ----------
            if (k < TT) {
                if ((k & 7) == 0 && k + CH < TT) {      // refill next x chunk
                    const int tloc = (tid & 255) >> 5, ss = tid & 31;
                    const int tg = k + CH + tloc;
                    const float* px = x + ((size_t)(s0 + ss) * TT + tg) * DD;
                    f32x4 a, b;
                    a[0] = px[0]; a[1] = px[1]; a[2] = px[2]; a[3] = px[3];
                    b[0] = px[4]; b[1] = px[5]; b[2] = px[6]; b[3] = 1.0f;
                    const int nb = ((k >> 3) & 1) ^ 1;
                    xs[nb][tloc][ss] = pack8(a, b);
                }
                const int cb = (k >> 3) & 1, tt = k & 7;
                const int rp = (k - 1) & 1;             // h1(k-1) parity

#pragma unroll
                for (int st = 0; st < 2; ++st)
#pragma unroll
                    for (int t4 = 0; t4 < 4; ++t4) aA[st][t4] = (f32x4){0, 0, 0, 0};

                __builtin_amdgcn_s_setprio(1);
#pragma unroll
                for (int st = 0; st < 2; ++st) {
                    f16x8 ax = z8;
                    if (kg == 0) ax = xs[cb][tt][16 * st + col];
                    TERM2(aA[st][0], WXh[0], WXl[0], ax)
                    TERM2(aA[st][1], WXh[1], WXl[1], ax)
                    TERM2(aA[st][2], WXh[2], WXl[2], ax)
                    TERM2(aA[st][3], WXh[3], WXl[3], ax)
#pragma unroll
                    for (int kf = 0; kf < 2; ++kf) {
                        const f16x8 dh = *(const f16x8*)&h1[rp][16 * st + col][32 * kf + 8 * kg];
                        TERM2(aA[st][0], W0h[0][kf], W0l[0][kf], dh)
                        TERM2(aA[st][1], W0h[1][kf], W0l[1][kf], dh)
                        TERM2(aA[st][2], W0h[2][kf], W0l[2][kf], dh)
                        TERM2(aA[st][3], W0h[3][kf], W0l[3][kf], dh)
                    }
                }
                __builtin_amdgcn_s_setprio(0);
            }
            __syncthreads();   // B1
            // ---------- Segment B: L0 cell update for step k ----------
            if (k < TT) {
                const int wp = k & 1;
#pragma unroll
                for (int st = 0; st < 2; ++st)
                    cell_update(aA[st][0], aA[st][1], aA[st][2], aA[st][3], c1[st],
                                &h1[wp][16 * st + col][ub]);
            }
            __syncthreads();   // B2
        }
    } else {
        // ==================== LAYER-1 ENGINE (waves 4-7) ====================
        f16x8 W1h[4][4], W1l[4][4];   // kf 0..1: w_ih1 (h1 input); kf 2..3: w_hh1 (h2 input)
        f32x4 bias1[4];
#pragma unroll
        for (int t4 = 0; t4 < 4; ++t4) {
            const int row = 64 * t4 + 16 * q + col;
            const int rr  = 64 * t4 + 16 * q + 4 * kg;
            bias1[t4] = *(const f32x4*)(b_ih1 + rr) + *(const f32x4*)(b_hh1 + rr);
#pragma unroll
            for (int kf = 0; kf < 4; ++kf) {
                const float* base = (kf < 2) ? (w_ih1 + (size_t)row * HH + 32 * kf)
                                             : (w_hh1 + (size_t)row * HH + 32 * (kf - 2));
                const float* p = base + 8 * kg;
                wsplit8(*(const f32x4*)p, *(const f32x4*)(p + 4), W1h[t4][kf], W1l[t4][kf]);
            }
        }
        f32x4 c2[2] = {{0,0,0,0},{0,0,0,0}};
        f32x4 aB[2][4];

#pragma unroll 1
        for (int k = 0; k <= TT + 1; ++k) {
            // ---------- Segment A: L1 cell update for step k-2 ----------
            if (k >= 2) {
                const int wp = k & 1;                   // (k-2)&1
#pragma unroll
                for (int st = 0; st < 2; ++st)
                    cell_update(aB[st][0], aB[st][1], aB[st][2], aB[st][3], c2[st],
                                &h2[wp][16 * st + col][ub]);
            }
            __syncthreads();   // B1
            // ---------- Segment B: L1 MFMA for step k-1 ----------
            if (k >= 1 && k <= TT) {
                const int rp1 = (k - 1) & 1;            // h1(k-1) parity
                const int rp2 = k & 1;                  // h2(k-2) parity

#pragma unroll
                for (int st = 0; st < 2; ++st)
#pragma unroll
                    for (int t4 = 0; t4 < 4; ++t4) aB[st][t4] = bias1[t4];

                __builtin_amdgcn_s_setprio(1);
#pragma unroll
                for (int st = 0; st < 2; ++st) {
#pragma unroll
                    for (int kf = 0; kf < 2; ++kf) {    // h1(k-1) input
                        const f16x8 dh = *(const f16x8*)&h1[rp1][16 * st + col][32 * kf + 8 * kg];
                        TERM2(aB[st][0], W1h[0][kf], W1l[0][kf], dh)
                        TERM2(aB[st][1], W1h[1][kf], W1l[1][kf], dh)
                        TERM2(aB[st][2], W1h[2][kf], W1l[2][kf], dh)
                        TERM2(aB[st][3], W1h[3][kf], W1l[3][kf], dh)
                    }
#pragma unroll
                    for (int kf = 0; kf < 2; ++kf) {    // h2(k-2) input
                        const f16x8 eh = *(const f16x8*)&h2[rp2][16 * st + col][32 * kf + 8 * kg];
                        TERM2(aB[st][0], W1h[0][kf + 2], W1l[0][kf + 2], eh)
                        TERM2(aB[st][1], W1h[1][kf + 2], W1l[1][kf + 2], eh)
                        TERM2(aB[st][2], W1h[2][kf + 2], W1l[2][kf + 2], eh)
                        TERM2(aB[st][3], W1h[3][kf + 2], W1l[3][kf + 2], eh)
                    }
                }
                __builtin_amdgcn_s_setprio(0);
            }
            __syncthreads();   // B2
        }
    }

    // ---------------- FC head on final h2 = h2(TT-1), parity (TT+1)&1 ----------------
    if (tid < NS * 4) {
        const int s = tid >> 2, k = tid & 3;
        const int fp = (TT + 1) & 1;
        float a = fc_b[k];
#pragma unroll
        for (int j = 0; j < HH; ++j)
            a = fmaf((float)h2[fp][s][j], fc_w[k * HH + j], a);
        out[(size_t)(s0 + s) * 4 + k] = a;
    }
}

extern "C" void kernel_launch(void* const* d_in, const int* in_sizes, int n_in,
                              void* d_out, int out_size, void* d_ws, size_t ws_size,
                              hipStream_t stream) {
    const float* x     = (const float*)d_in[0];
    const float* w_ih0 = (const float*)d_in[1];
    const float* w_hh0 = (const float*)d_in[2];
    const float* b_ih0 = (const float*)d_in[3];
    const float* b_hh0 = (const float*)d_in[4];
    const float* w_ih1 = (const float*)d_in[5];
    const float* w_hh1 = (const float*)d_in[6];
    const float* b_ih1 = (const float*)d_in[7];
    const float* b_hh1 = (const float*)d_in[8];
    const float* fc_w  = (const float*)d_in[9];
    const float* fc_b  = (const float*)d_in[10];
    float* out = (float*)d_out;

    dim3 grid(BB / NS), block(NTH);
    weather_lstm_mfma<<<grid, block, 0, stream>>>(
        x, w_ih0, w_hh0, b_ih0, b_hh0,
        w_ih1, w_hh1, b_ih1, b_hh1, fc_w, fc_b, out);
}